// Round 1
// 272.725 us; speedup vs baseline: 1.0064x; 1.0064x over previous
//
#include <hip/hip_runtime.h>
#include <stdint.h>

// B=8, S=1024, H=1024, NH=16, HD=64
typedef __attribute__((ext_vector_type(8))) __bf16 bf16x8;
typedef __attribute__((ext_vector_type(8))) unsigned short ushortx8;
typedef __attribute__((ext_vector_type(4))) unsigned short ushortx4;
typedef __attribute__((ext_vector_type(4))) short short4v;
typedef __attribute__((ext_vector_type(4))) float floatx4;

#define LOG2E 1.4426950408889634f
#define QSCALE 0.18033688011112043f   // 0.125 * log2e

#define ASYNC16(g, l) __builtin_amdgcn_global_load_lds( \
    (__attribute__((address_space(1))) void*)(g),       \
    (__attribute__((address_space(3))) void*)(l), 16, 0, 0)

__device__ __forceinline__ unsigned short f2bf(float f) {
    unsigned int u = __float_as_uint(f);
    u += 0x7fffu + ((u >> 16) & 1u);   // round-to-nearest-even
    return (unsigned short)(u >> 16);
}
__device__ __forceinline__ float bf2f(unsigned short u) {
    return __uint_as_float((unsigned)u << 16);
}

__device__ __forceinline__ floatx4 mfma32(bf16x8 a, bf16x8 b, floatx4 c) {
    return __builtin_amdgcn_mfma_f32_16x16x32_bf16(a, b, c, 0, 0, 0);
}
__device__ __forceinline__ floatx4 mfma16(short4v a, short4v b, floatx4 c) {
    return __builtin_amdgcn_mfma_f32_16x16x16bf16_1k(a, b, c, 0, 0, 0);
}

// ---------------- fp32 -> bf16 converts (hidden + all 4 weights, one launch) --------
__global__ __launch_bounds__(256) void cvt_all(
    const float* __restrict__ hidden,
    const float* __restrict__ Wq, const float* __restrict__ Wk,
    const float* __restrict__ Wv, const float* __restrict__ Wo,
    unsigned short* __restrict__ hid_bf,
    unsigned short* __restrict__ oqkv, unsigned short* __restrict__ oo)
{
    const float* src;
    unsigned short* dst;
    int i;
    if (blockIdx.x < 4096) {
        src = hidden; dst = hid_bf;
        i = blockIdx.x * 256 + threadIdx.x;          // < 1048576
    } else {
        int blk = (blockIdx.x - 4096) >> 9;
        src = (blk == 0) ? Wq : (blk == 1) ? Wk : (blk == 2) ? Wv : Wo;
        dst = (blk == 3) ? oo : oqkv + (size_t)blk * 1048576;
        i = ((blockIdx.x - 4096) & 511) * 256 + threadIdx.x;   // < 131072
    }
    const float4* p = (const float4*)src + (size_t)i * 2;
    float4 a = p[0], b = p[1];
    ushortx8 o;
    o[0] = f2bf(a.x); o[1] = f2bf(a.y); o[2] = f2bf(a.z); o[3] = f2bf(a.w);
    o[4] = f2bf(b.x); o[5] = f2bf(b.y); o[6] = f2bf(b.z); o[7] = f2bf(b.w);
    *((ushortx8*)dst + i) = o;
}

// ---------- shared BK=64 K-loop, 128x128 tile, swizzled LDS (used by gemm_proj) ----
template<bool SWAP>
__device__ __forceinline__ void kloop_bk64(
    const unsigned short* __restrict__ Ag,
    const unsigned short* __restrict__ Wg,
    unsigned short* As, unsigned short* Bs,
    int wm, int wn, int l16, int quad, int t,
    floatx4 acc[4][4])
{
#pragma unroll 1
    for (int k0 = 0; k0 < 1024; k0 += 64) {
        __syncthreads();
#pragma unroll
        for (int i = 0; i < 4; i++) {
            ASYNC16(Ag + (size_t)i * 32 * 1024 + k0, As + i * 2048 + t * 8);
            ASYNC16(Wg + (size_t)i * 32 * 1024 + k0, Bs + i * 2048 + t * 8);
        }
        __syncthreads();
#pragma unroll
        for (int s = 0; s < 2; s++) {
            int pb = ((s * 4 + quad) ^ (l16 & 7)) * 8;
            bf16x8 af[4], bfr[4];
#pragma unroll
            for (int mt = 0; mt < 4; mt++)
                af[mt] = *(const bf16x8*)(As + (wm + mt * 16 + l16) * 64 + pb);
#pragma unroll
            for (int nt = 0; nt < 4; nt++)
                bfr[nt] = *(const bf16x8*)(Bs + (wn + nt * 16 + l16) * 64 + pb);
            if (SWAP) {
#pragma unroll
                for (int ft = 0; ft < 4; ft++)
#pragma unroll
                    for (int st = 0; st < 4; st++)
                        acc[ft][st] = mfma32(bfr[ft], af[st], acc[ft][st]);
            } else {
#pragma unroll
                for (int mt = 0; mt < 4; mt++)
#pragma unroll
                    for (int nt = 0; nt < 4; nt++)
                        acc[mt][nt] = mfma32(af[mt], bfr[nt], acc[mt][nt]);
            }
        }
    }
}

// ---------------- merged QKV GEMM: 256x256 tile, 8-wave, 4-phase pipelined K-loop ---
// grid (32, 12), 512 threads. y 0-3: Q (prescaled QSCALE), 4-7: K, 8-11: V (permuted
// [b,h,d,s']). LDS: 2 dbuf x (256x64 A + 256x64 B) = 128 KiB. Staging unit = 64 rows
// x 64 cols (8 KB = 1 global_load_lds_dwordx4/thread), linear LDS dest + pre-swizzled
// global source (16B-chunk p of row r holds logical chunk p^(r&7) -> ds_read conflict
// free, same scheme as the 2-phase kernel which measured 0 bank conflicts).
//
// Phase p (0..3) of K-tile kt: ds_read A-frags st={2p,2p+1} (x2 ksteps); phase 0 also
// reads all 8 B-frags (held in regs for the whole tile). Stage schedule (1 unit = 1
// vmcnt tick/thread; region freed by the previous phase's end barrier + lgkmcnt(0)):
//   ph0: issue A1,A3 of kt+1 (other buffer)   ph1: B0,B1 of kt+2 (this buffer)
//   ph2: A0,A2 of kt+2                        ph3: B2,B3 of kt+2
// Tile-end s_waitcnt vmcnt(6) leaves exactly kt+2's 6 issued units in flight and
// proves all of kt+1 landed. Never drains to 0 except entering the last tile.
__global__ __launch_bounds__(512, 2) void gemm_qkv(
    const unsigned short* __restrict__ A,   // [8192][1024] bf16
    const unsigned short* __restrict__ W,   // [Wq;Wk;Wv] [3072][1024]
    const float* __restrict__ bq, const float* __restrict__ bk, const float* __restrict__ bv,
    unsigned short* __restrict__ Qo, unsigned short* __restrict__ Ko,
    unsigned short* __restrict__ Vo)
{
    __shared__ unsigned short As[2][16384];   // [buf][256*64]
    __shared__ unsigned short Bs[2][16384];
    const int t = threadIdx.x;
    const int lane = t & 63, quad = lane >> 4, l16 = lane & 15;
    const int wid = t >> 6;
    const int wm = (wid >> 2) * 128;   // seq offset of wave within tile
    const int wn = (wid & 3) * 64;     // feature offset of wave within tile
    const int rr = t >> 3;             // staging row within 64-row unit
    const int cc = ((t & 7) ^ (rr & 7)) * 8;   // pre-swizzled global col (elements)
    const int t8 = t * 8;              // linear LDS ushort offset within unit

    const unsigned short* Ab = A + ((size_t)blockIdx.x * 256 + rr) * 1024 + cc;
    const unsigned short* Wb = W + ((size_t)blockIdx.y * 256 + rr) * 1024 + cc;

#define SA(bf_, u_, kt_) ASYNC16(Ab + (size_t)(u_) * 65536 + (kt_) * 64, &As[bf_][(u_) * 4096 + t8])
#define SB(bf_, u_, kt_) ASYNC16(Wb + (size_t)(u_) * 65536 + (kt_) * 64, &Bs[bf_][(u_) * 4096 + t8])

    // prologue: tile0 complete (8 units), tile1 partial (B0,B1,A0,A2,B2,B3)
    SA(0, 0, 0); SA(0, 1, 0); SA(0, 2, 0); SA(0, 3, 0);
    SB(0, 0, 0); SB(0, 1, 0); SB(0, 2, 0); SB(0, 3, 0);
    SB(1, 0, 1); SB(1, 1, 1); SA(1, 0, 1); SA(1, 2, 1); SB(1, 2, 1); SB(1, 3, 1);
    asm volatile("s_waitcnt vmcnt(6)" ::: "memory");   // tile0 landed, tile1's 6 in flight
    __builtin_amdgcn_s_barrier();

    floatx4 acc[4][8] = {};   // [ft][st]

#pragma unroll 1
    for (int kt = 0; kt < 16; ++kt) {
        const int cur = kt & 1, nb = cur ^ 1;
        const unsigned short* Ac = As[cur];
        const unsigned short* Bc = Bs[cur];
        bf16x8 bfr[4][2];

        // ---------------- phase 0: st 0,1 + all B frags ----------------
        {
            bf16x8 a0[2][2];
#pragma unroll
            for (int j = 0; j < 2; ++j)
#pragma unroll
                for (int s = 0; s < 2; ++s)
                    a0[j][s] = *(const bf16x8*)(Ac + (wm + j * 16 + l16) * 64 +
                                                ((s * 4 + quad) ^ (l16 & 7)) * 8);
#pragma unroll
            for (int ft = 0; ft < 4; ++ft)
#pragma unroll
                for (int s = 0; s < 2; ++s)
                    bfr[ft][s] = *(const bf16x8*)(Bc + (wn + ft * 16 + l16) * 64 +
                                                  ((s * 4 + quad) ^ (l16 & 7)) * 8);
            if (kt < 15) { SA(nb, 1, kt + 1); SA(nb, 3, kt + 1); }
            __builtin_amdgcn_s_barrier();
            asm volatile("s_waitcnt lgkmcnt(0)" ::: "memory");
            __builtin_amdgcn_sched_barrier(0);
            __builtin_amdgcn_s_setprio(1);
#pragma unroll
            for (int ft = 0; ft < 4; ++ft)
#pragma unroll
                for (int j = 0; j < 2; ++j) {
                    acc[ft][j] = mfma32(bfr[ft][0], a0[j][0], acc[ft][j]);
                    acc[ft][j] = mfma32(bfr[ft][1], a0[j][1], acc[ft][j]);
                }
            __builtin_amdgcn_s_setprio(0);
            __builtin_amdgcn_s_barrier();
        }
        // ---------------- phases 1..3 ----------------
#pragma unroll
        for (int p = 1; p < 4; ++p) {
            bf16x8 a0[2][2];
#pragma unroll
            for (int j = 0; j < 2; ++j)
#pragma unroll
                for (int s = 0; s < 2; ++s)
                    a0[j][s] = *(const bf16x8*)(Ac + (wm + (p * 2 + j) * 16 + l16) * 64 +
                                                ((s * 4 + quad) ^ (l16 & 7)) * 8);
            if (kt < 14) {
                if (p == 1)      { SB(cur, 0, kt + 2); SB(cur, 1, kt + 2); }
                else if (p == 2) { SA(cur, 0, kt + 2); SA(cur, 2, kt + 2); }
                else             { SB(cur, 2, kt + 2); SB(cur, 3, kt + 2); }
            }
            __builtin_amdgcn_s_barrier();
            asm volatile("s_waitcnt lgkmcnt(0)" ::: "memory");
            __builtin_amdgcn_sched_barrier(0);
            __builtin_amdgcn_s_setprio(1);
#pragma unroll
            for (int ft = 0; ft < 4; ++ft)
#pragma unroll
                for (int j = 0; j < 2; ++j) {
                    acc[ft][p * 2 + j] = mfma32(bfr[ft][0], a0[j][0], acc[ft][p * 2 + j]);
                    acc[ft][p * 2 + j] = mfma32(bfr[ft][1], a0[j][1], acc[ft][p * 2 + j]);
                }
            __builtin_amdgcn_s_setprio(0);
            if (p < 3) {
                __builtin_amdgcn_s_barrier();
            } else {
                if (kt < 14)       { asm volatile("s_waitcnt vmcnt(6)" ::: "memory"); }
                else if (kt == 14) { asm volatile("s_waitcnt vmcnt(0)" ::: "memory"); }
                if (kt < 15) __builtin_amdgcn_s_barrier();
            }
        }
    }
#undef SA
#undef SB

    const int y = blockIdx.y;
    if (y < 8) {
        // Q/K: [b,h,s,d]; lane owns 4 consecutive d -> 8B stores. Q gets QSCALE.
        const float* bp = (y < 4) ? bq : bk;
        unsigned short* op = (y < 4) ? Qo : Ko;
        const float sc = (y < 4) ? QSCALE : 1.0f;
#pragma unroll
        for (int ft = 0; ft < 4; ++ft) {
            const int featg = (y & 3) * 256 + wn + ft * 16 + quad * 4;
            const float4 b4 = *(const float4*)(bp + featg);
            const int h = featg >> 6, d = featg & 63;
#pragma unroll
            for (int st = 0; st < 8; ++st) {
                const int sg = blockIdx.x * 256 + wm + st * 16 + l16;
                const int b = sg >> 10, s = sg & 1023;
                ushortx4 o4;
                o4[0] = f2bf((acc[ft][st][0] + b4.x) * sc);
                o4[1] = f2bf((acc[ft][st][1] + b4.y) * sc);
                o4[2] = f2bf((acc[ft][st][2] + b4.z) * sc);
                o4[3] = f2bf((acc[ft][st][3] + b4.w) * sc);
                *(ushortx4*)(op + (((size_t)(b * 16 + h) * 1024 + s) * 64 + d)) = o4;
            }
        }
    } else {
        // V: [b,h,d,s'] with per-64-window PV-fragment permutation (nt = st&3):
        // s = 64a + nt*16 + q*4 + j  ->  s' = 64a + (nt>>1)*32 + q*8 + (nt&1)*4 + j
#pragma unroll
        for (int ft = 0; ft < 4; ++ft) {
            const int featg = (y & 3) * 256 + wn + ft * 16 + quad * 4;
            const float4 b4 = *(const float4*)(bv + featg);
#pragma unroll
            for (int r = 0; r < 4; ++r) {
                const int feat = featg + r;
                const int h = feat >> 6, d = feat & 63;
                const float bias = (r == 0) ? b4.x : (r == 1) ? b4.y : (r == 2) ? b4.z : b4.w;
#pragma unroll
                for (int st = 0; st < 8; ++st) {
                    const int sg = blockIdx.x * 256 + wm + st * 16 + l16;
                    const int b = sg >> 10, s = sg & 1023;
                    const int sp = (s & ~63) + ((st >> 1) & 1) * 32 + (l16 >> 2) * 8 +
                                   (st & 1) * 4 + (l16 & 3);
                    Vo[((size_t)(b * 16 + h) * 64 + d) * 1024 + sp] = f2bf(acc[ft][st][r] + bias);
                }
            }
        }
    }
}

// ---------------- flash attention: 128-row Q tile, direct-global Q fragments ----------
// grid (128, 8): x = head (id%8 = head%8 -> one head per XCD), y = 128-row q-tile.
__global__ __launch_bounds__(256) void attn(
    const unsigned short* __restrict__ Q,   // [b,h,s,d] (scaled by 0.125*log2e)
    const unsigned short* __restrict__ Kg,  // [b,h,s,d]
    const unsigned short* __restrict__ Vt,  // [b,h,d,s'] (permuted)
    const float* __restrict__ mask,         // [B][S]
    unsigned short* __restrict__ ctx)       // [B,S,H] bf16
{
    __shared__ unsigned short Ks[64 * 64];
    __shared__ unsigned short Vs[64 * 64];
    __shared__ float Msall[1024];

    const int t = threadIdx.x;
    const int wave = t >> 6, lane = t & 63, quad = lane >> 4, l16 = lane & 15;
    const int s7 = l16 & 7;
    const int head = blockIdx.x;
    const int b = head >> 4, h = head & 15;
    const int q0 = blockIdx.y * 128;
    const unsigned short* Qh = Q + (size_t)head * 65536;
    const unsigned short* Kh = Kg + (size_t)head * 65536;
    const unsigned short* Vh = Vt + (size_t)head * 65536;

    const int srow = t >> 3;
    const int scol = ((t & 7) ^ (srow & 7)) * 8;

    {   // mask row -> LDS, pre-scaled by log2e
        float4 m4 = *(const float4*)(mask + b * 1024 + t * 4);
        m4.x *= LOG2E; m4.y *= LOG2E; m4.z *= LOG2E; m4.w *= LOG2E;
        *(float4*)(Msall + t * 4) = m4;
    }

    // Q fragments direct from global: qf[qg][s][j] = Q[q0+wave*32+qg*16+l16][s*32+quad*8+j]
    bf16x8 qf[2][2];
#pragma unroll
    for (int qg = 0; qg < 2; qg++) {
        const unsigned short* qp = Qh + (size_t)(q0 + wave * 32 + qg * 16 + l16) * 64 + quad * 8;
        qf[qg][0] = *(const bf16x8*)(qp);
        qf[qg][1] = *(const bf16x8*)(qp + 32);
    }

    float rs0 = 0.f, rs1 = 0.f;
    floatx4 o_acc[2][4] = {};   // [qg][dt]: O^T rows d = dt*16+quad*4+r, col q = l16

    for (int k0 = 0; k0 < 1024; k0 += 64) {
        __syncthreads();
#pragma unroll
        for (int i = 0; i < 2; i++) {
            ASYNC16(Kh + (size_t)(k0 + i * 32 + srow) * 64 + scol, Ks + i * 2048 + t * 8);
            ASYNC16(Vh + (size_t)(i * 32 + srow) * 1024 + k0 + scol, Vs + i * 2048 + t * 8);
        }
        __syncthreads();

        short4v pf0[4], pf1[4];
#pragma unroll
        for (int nt = 0; nt < 4; nt++) {
            int krow = nt * 16 + l16;
            bf16x8 kf0 = *(const bf16x8*)(Ks + krow * 64 + ((quad ^ s7) * 8));
            bf16x8 kf1 = *(const bf16x8*)(Ks + krow * 64 + (((4 + quad) ^ s7) * 8));
            floatx4 mk = *(const floatx4*)(Msall + k0 + nt * 16 + quad * 4);
            floatx4 z0 = {0.f, 0.f, 0.f, 0.f};
            z0 = mfma32(kf0, qf[0][0], z0);
            z0 = mfma32(kf1, qf[0][1], z0);
            floatx4 z1 = {0.f, 0.f, 0.f, 0.f};
            z1 = mfma32(kf0, qf[1][0], z1);
            z1 = mfma32(kf1, qf[1][1], z1);
#pragma unroll
            for (int r = 0; r < 4; r++) {
                float p0 = exp2f(z0[r] + mk[r]);
                float p1 = exp2f(z1[r] + mk[r]);
                rs0 += p0;
                rs1 += p1;
                pf0[nt][r] = (short)(__float_as_uint(p0) >> 16);
                pf1[nt][r] = (short)(__float_as_uint(p1) >> 16);
            }
        }

        // O^T += V^T P^T; Vs permuted so (nt,nt+1) fragments are one b128 read.
#pragma unroll
        for (int dt = 0; dt < 4; dt++) {
            int vrow = dt * 16 + l16;
            ushortx8 v01 = *(const ushortx8*)(Vs + vrow * 64 + ((quad ^ s7) * 8));
            ushortx8 v23 = *(const ushortx8*)(Vs + vrow * 64 + (((4 + quad) ^ s7) * 8));
            short4v vf0 = {(short)v01[0], (short)v01[1], (short)v01[2], (short)v01[3]};
            short4v vf1 = {(short)v01[4], (short)v01[5], (short)v01[6], (short)v01[7]};
            short4v vf2 = {(short)v23[0], (short)v23[1], (short)v23[2], (short)v23[3]};
            short4v vf3 = {(short)v23[4], (short)v23[5], (short)v23[6], (short)v23[7]};
            o_acc[0][dt] = mfma16(vf0, pf0[0], o_acc[0][dt]);
            o_acc[0][dt] = mfma16(vf1, pf0[1], o_acc[0][dt]);
            o_acc[0][dt] = mfma16(vf2, pf0[2], o_acc[0][dt]);
            o_acc[0][dt] = mfma16(vf3, pf0[3], o_acc[0][dt]);
            o_acc[1][dt] = mfma16(vf0, pf1[0], o_acc[1][dt]);
            o_acc[1][dt] = mfma16(vf1, pf1[1], o_acc[1][dt]);
            o_acc[1][dt] = mfma16(vf2, pf1[2], o_acc[1][dt]);
            o_acc[1][dt] = mfma16(vf3, pf1[3], o_acc[1][dt]);
        }
    }

#pragma unroll
    for (int qg = 0; qg < 2; qg++) {
        float v = (qg == 0) ? rs0 : rs1;
        v += __shfl_xor(v, 16);
        v += __shfl_xor(v, 32);
        float inv_l = 1.0f / v;
        int qrow = q0 + wave * 32 + qg * 16 + l16;
#pragma unroll
        for (int dt = 0; dt < 4; dt++) {
            ushortx4 o4;
#pragma unroll
            for (int r = 0; r < 4; r++) o4[r] = f2bf(o_acc[qg][dt][r] * inv_l);
            *(ushortx4*)(ctx + ((size_t)(b * 1024 + qrow)) * 1024 + h * 64 + dt * 16 + quad * 4) = o4;
        }
    }
}

// ---------------- out-proj GEMM + bias + bf16 residual -> x (bf16) ----------------
__global__ __launch_bounds__(256) void gemm_proj(
    const unsigned short* __restrict__ A,   // ctx bf16 [8192][1024]
    const unsigned short* __restrict__ W,   // Wo bf16 [1024][1024]
    const float* __restrict__ bo,
    const unsigned short* __restrict__ resid,  // hid_bf [8192][1024]
    unsigned short* __restrict__ X)         // bf16 [8192][1024]
{
    __shared__ unsigned short As[128 * 64];
    __shared__ unsigned short Bs[128 * 64];
    const int t = threadIdx.x;
    const int wave = t >> 6, lane = t & 63;
    const int quad = lane >> 4, l16 = lane & 15;
    const int wm = (wave >> 1) * 64, wn = (wave & 1) * 64;
    const int srow = t >> 3;
    const int scol = ((t & 7) ^ (srow & 7)) * 8;

    const unsigned short* Ag = A + ((size_t)blockIdx.x * 128 + srow) * 1024 + scol;
    const unsigned short* Wg = W + ((size_t)blockIdx.y * 128 + srow) * 1024 + scol;

    floatx4 acc[4][4] = {};
    kloop_bk64<false>(Ag, Wg, As, Bs, wm, wn, l16, quad, t, acc);

#pragma unroll
    for (int nt = 0; nt < 4; nt++) {
        int gn = blockIdx.y * 128 + wn + nt * 16 + l16;
        float bias = bo[gn];
#pragma unroll
        for (int mt = 0; mt < 4; mt++) {
#pragma unroll
            for (int r = 0; r < 4; r++) {
                int gm = blockIdx.x * 128 + wm + mt * 16 + quad * 4 + r;
                size_t off = (size_t)gm * 1024 + gn;
                X[off] = f2bf(acc[mt][nt][r] + bias + bf2f(resid[off]));
            }
        }
    }
}

// ---------------- LayerNorm: one block per token row (bf16 in, fp32 out) ------------
__global__ __launch_bounds__(256) void ln_k(const unsigned short* __restrict__ X,
                                            const float* __restrict__ g,
                                            const float* __restrict__ be,
                                            float* __restrict__ out)
{
    int row = blockIdx.x;
    int t = threadIdx.x;
    const unsigned short* xr = X + (size_t)row * 1024;
    ushortx4 xb = *(const ushortx4*)(xr + t * 4);
    float4 v;
    v.x = bf2f(xb[0]);
    v.y = bf2f(xb[1]);
    v.z = bf2f(xb[2]);
    v.w = bf2f(xb[3]);
    float s = v.x + v.y + v.z + v.w;
    float ss = v.x * v.x + v.y * v.y + v.z * v.z + v.w * v.w;
    for (int off = 1; off < 64; off <<= 1) {
        s += __shfl_xor(s, off);
        ss += __shfl_xor(ss, off);
    }
    __shared__ float red[8];
    int wave = t >> 6, lane = t & 63;
    if (lane == 0) { red[wave] = s; red[4 + wave] = ss; }
    __syncthreads();
    s = red[0] + red[1] + red[2] + red[3];
    ss = red[4] + red[5] + red[6] + red[7];
    float mu = s * (1.f / 1024.f);
    float var = ss * (1.f / 1024.f) - mu * mu;
    float inv = rsqrtf(var + 1e-12f);
    float4 gv = *(const float4*)(g + t * 4);
    float4 bv = *(const float4*)(be + t * 4);
    float4 o;
    o.x = (v.x - mu) * inv * gv.x + bv.x;
    o.y = (v.y - mu) * inv * gv.y + bv.y;
    o.z = (v.z - mu) * inv * gv.z + bv.z;
    o.w = (v.w - mu) * inv * gv.w + bv.w;
    *(float4*)(out + (size_t)row * 1024 + t * 4) = o;
}

extern "C" void kernel_launch(void* const* d_in, const int* in_sizes, int n_in,
                              void* d_out, int out_size, void* d_ws, size_t ws_size,
                              hipStream_t stream)
{
    const float* hidden = (const float*)d_in[0];
    const float* mask   = (const float*)d_in[1];
    const float* Wq = (const float*)d_in[2];
    const float* bq = (const float*)d_in[3];
    const float* Wk = (const float*)d_in[4];
    const float* bk = (const float*)d_in[5];
    const float* Wv = (const float*)d_in[6];
    const float* bv = (const float*)d_in[7];
    const float* Wo = (const float*)d_in[8];
    const float* bo = (const float*)d_in[9];
    const float* gamma = (const float*)d_in[10];
    const float* beta  = (const float*)d_in[11];
    float* out = (float*)d_out;

    char* ws = (char*)d_ws;
    // layout (bytes): hid_bf 16M | wqkv_bf 6M | wo_bf 2M | vt_bf 16M | ctx_bf 16M | q_bf 16M | k_bf 16M
    // x (bf16, 16M) aliases q_bf (dead after attn). total 88M.
    unsigned short* hid_bf  = (unsigned short*)(ws + 0);
    unsigned short* wqkv_bf = (unsigned short*)(ws + 16777216);
    unsigned short* wo_bf   = (unsigned short*)(ws + 23068672);
    unsigned short* vt_bf   = (unsigned short*)(ws + 25165824);
    unsigned short* ctx_bf  = (unsigned short*)(ws + 41943040);
    unsigned short* q_bf    = (unsigned short*)(ws + 58720256);
    unsigned short* k_bf    = (unsigned short*)(ws + 75497472);
    unsigned short* x_bf    = (unsigned short*)(ws + 58720256);

    cvt_all<<<6144, 256, 0, stream>>>(hidden, Wq, Wk, Wv, Wo, hid_bf, wqkv_bf, wo_bf);

    gemm_qkv<<<dim3(32, 12), 512, 0, stream>>>(hid_bf, wqkv_bf, bq, bk, bv, q_bf, k_bf, vt_bf);
    attn<<<dim3(128, 8), 256, 0, stream>>>(q_bf, k_bf, vt_bf, mask, ctx_bf);
    gemm_proj<<<dim3(64, 8), 256, 0, stream>>>(ctx_bf, wo_bf, bo, hid_bf, x_bf);
    ln_k<<<8192, 256, 0, stream>>>(x_bf, gamma, beta, out);
}

// Round 2
// 268.933 us; speedup vs baseline: 1.0206x; 1.0141x over previous
//
#include <hip/hip_runtime.h>
#include <stdint.h>

// B=8, S=1024, H=1024, NH=16, HD=64
typedef __attribute__((ext_vector_type(8))) __bf16 bf16x8;
typedef __attribute__((ext_vector_type(8))) unsigned short ushortx8;
typedef __attribute__((ext_vector_type(4))) unsigned short ushortx4;
typedef __attribute__((ext_vector_type(4))) short short4v;
typedef __attribute__((ext_vector_type(4))) float floatx4;

#define LOG2E 1.4426950408889634f
#define QSCALE 0.18033688011112043f   // 0.125 * log2e

#define ASYNC16(g, l) __builtin_amdgcn_global_load_lds( \
    (__attribute__((address_space(1))) void*)(g),       \
    (__attribute__((address_space(3))) void*)(l), 16, 0, 0)

__device__ __forceinline__ unsigned short f2bf(float f) {
    unsigned int u = __float_as_uint(f);
    u += 0x7fffu + ((u >> 16) & 1u);   // round-to-nearest-even
    return (unsigned short)(u >> 16);
}
__device__ __forceinline__ float bf2f(unsigned short u) {
    return __uint_as_float((unsigned)u << 16);
}

__device__ __forceinline__ floatx4 mfma32(bf16x8 a, bf16x8 b, floatx4 c) {
    return __builtin_amdgcn_mfma_f32_16x16x32_bf16(a, b, c, 0, 0, 0);
}
__device__ __forceinline__ floatx4 mfma16(short4v a, short4v b, floatx4 c) {
    return __builtin_amdgcn_mfma_f32_16x16x16bf16_1k(a, b, c, 0, 0, 0);
}

// ---------------- fp32 -> bf16 converts (hidden + all 4 weights, one launch) --------
__global__ __launch_bounds__(256) void cvt_all(
    const float* __restrict__ hidden,
    const float* __restrict__ Wq, const float* __restrict__ Wk,
    const float* __restrict__ Wv, const float* __restrict__ Wo,
    unsigned short* __restrict__ hid_bf,
    unsigned short* __restrict__ oqkv, unsigned short* __restrict__ oo)
{
    const float* src;
    unsigned short* dst;
    int i;
    if (blockIdx.x < 4096) {
        src = hidden; dst = hid_bf;
        i = blockIdx.x * 256 + threadIdx.x;          // < 1048576
    } else {
        int blk = (blockIdx.x - 4096) >> 9;
        src = (blk == 0) ? Wq : (blk == 1) ? Wk : (blk == 2) ? Wv : Wo;
        dst = (blk == 3) ? oo : oqkv + (size_t)blk * 1048576;
        i = ((blockIdx.x - 4096) & 511) * 256 + threadIdx.x;   // < 131072
    }
    const float4* p = (const float4*)src + (size_t)i * 2;
    float4 a = p[0], b = p[1];
    ushortx8 o;
    o[0] = f2bf(a.x); o[1] = f2bf(a.y); o[2] = f2bf(a.z); o[3] = f2bf(a.w);
    o[4] = f2bf(b.x); o[5] = f2bf(b.y); o[6] = f2bf(b.z); o[7] = f2bf(b.w);
    *((ushortx8*)dst + i) = o;
}

// ---------- shared BK=64 K-loop, 128x128 tile, swizzled LDS (used by gemm_proj) ----
template<bool SWAP>
__device__ __forceinline__ void kloop_bk64(
    const unsigned short* __restrict__ Ag,
    const unsigned short* __restrict__ Wg,
    unsigned short* As, unsigned short* Bs,
    int wm, int wn, int l16, int quad, int t,
    floatx4 acc[4][4])
{
#pragma unroll 1
    for (int k0 = 0; k0 < 1024; k0 += 64) {
        __syncthreads();
#pragma unroll
        for (int i = 0; i < 4; i++) {
            ASYNC16(Ag + (size_t)i * 32 * 1024 + k0, As + i * 2048 + t * 8);
            ASYNC16(Wg + (size_t)i * 32 * 1024 + k0, Bs + i * 2048 + t * 8);
        }
        __syncthreads();
#pragma unroll
        for (int s = 0; s < 2; s++) {
            int pb = ((s * 4 + quad) ^ (l16 & 7)) * 8;
            bf16x8 af[4], bfr[4];
#pragma unroll
            for (int mt = 0; mt < 4; mt++)
                af[mt] = *(const bf16x8*)(As + (wm + mt * 16 + l16) * 64 + pb);
#pragma unroll
            for (int nt = 0; nt < 4; nt++)
                bfr[nt] = *(const bf16x8*)(Bs + (wn + nt * 16 + l16) * 64 + pb);
            if (SWAP) {
#pragma unroll
                for (int ft = 0; ft < 4; ft++)
#pragma unroll
                    for (int st = 0; st < 4; st++)
                        acc[ft][st] = mfma32(bfr[ft], af[st], acc[ft][st]);
            } else {
#pragma unroll
                for (int mt = 0; mt < 4; mt++)
#pragma unroll
                    for (int nt = 0; nt < 4; nt++)
                        acc[mt][nt] = mfma32(af[mt], bfr[nt], acc[mt][nt]);
            }
        }
    }
}

// ---------------- merged QKV GEMM: 256x192 tile, 8-wave, 4-phase pipelined K-loop ---
// grid (32, 16) = 512 blocks, 512 threads. 512 tiles / 256 CUs @ 1 block/CU (112 KiB
// LDS) = 2 perfectly balanced rounds (vs 384-block grid's 1.5 -> 2-round imbalance).
// N=192 straddles the Q/K/V 1024-feature boundaries, so output routing (Q scale /
// K / V permute) is per-16-wide-feature-fragment (wave-uniform branch).
//
// LDS: 2 dbuf x (256x64 A + 192x64 B). Staging unit = 64 rows x 64 cols (8 KB = 1
// global_load_lds_dwordx4/thread), linear LDS dest + pre-swizzled global source.
// Per tile 7 units: A0..A3, B0..B2. Issue schedule (region freed by the previous
// phase's end barrier):
//   ph0: A1,A3 of kt+1 (other buffer)   ph1: B0,B1 of kt+2 (this buffer)
//   ph2: A0,A2 of kt+2                  ph3: B2 of kt+2
// Tile-end s_waitcnt vmcnt(5) leaves exactly kt+2's 5 issued units in flight and
// proves all of kt+1 landed. Drains to 0 only entering the last tile.
__global__ __launch_bounds__(512, 2) void gemm_qkv(
    const unsigned short* __restrict__ A,   // [8192][1024] bf16
    const unsigned short* __restrict__ W,   // [Wq;Wk;Wv] [3072][1024]
    const float* __restrict__ bq, const float* __restrict__ bk, const float* __restrict__ bv,
    unsigned short* __restrict__ Qo, unsigned short* __restrict__ Ko,
    unsigned short* __restrict__ Vo)
{
    __shared__ unsigned short As[2][16384];   // [buf][256*64]
    __shared__ unsigned short Bs[2][12288];   // [buf][192*64]
    const int t = threadIdx.x;
    const int lane = t & 63, quad = lane >> 4, l16 = lane & 15;
    const int wid = t >> 6;
    const int wm = (wid >> 2) * 128;   // seq offset of wave within tile
    const int wn = (wid & 3) * 48;     // feature offset of wave within tile
    const int rr = t >> 3;             // staging row within 64-row unit
    const int cc = ((t & 7) ^ (rr & 7)) * 8;   // pre-swizzled global col (elements)
    const int t8 = t * 8;              // linear LDS ushort offset within unit

    const unsigned short* Ab = A + ((size_t)blockIdx.x * 256 + rr) * 1024 + cc;
    const unsigned short* Wb = W + ((size_t)blockIdx.y * 192 + rr) * 1024 + cc;

#define SA(bf_, u_, kt_) ASYNC16(Ab + (size_t)(u_) * 65536 + (kt_) * 64, &As[bf_][(u_) * 4096 + t8])
#define SB(bf_, u_, kt_) ASYNC16(Wb + (size_t)(u_) * 65536 + (kt_) * 64, &Bs[bf_][(u_) * 4096 + t8])

    // prologue: tile0 complete (7 units), tile1 partial (B0,B1,A0,A2,B2)
    SA(0, 0, 0); SA(0, 1, 0); SA(0, 2, 0); SA(0, 3, 0);
    SB(0, 0, 0); SB(0, 1, 0); SB(0, 2, 0);
    SB(1, 0, 1); SB(1, 1, 1); SA(1, 0, 1); SA(1, 2, 1); SB(1, 2, 1);
    asm volatile("s_waitcnt vmcnt(5)" ::: "memory");   // tile0 landed, tile1's 5 in flight
    __builtin_amdgcn_s_barrier();

    floatx4 acc[3][8] = {};   // [ft][st]

#pragma unroll 1
    for (int kt = 0; kt < 16; ++kt) {
        const int cur = kt & 1, nb = cur ^ 1;
        const unsigned short* Ac = As[cur];
        const unsigned short* Bc = Bs[cur];
        bf16x8 bfr[3][2];

        // ---------------- phase 0: st 0,1 + all B frags ----------------
        {
            bf16x8 a0[2][2];
#pragma unroll
            for (int j = 0; j < 2; ++j)
#pragma unroll
                for (int s = 0; s < 2; ++s)
                    a0[j][s] = *(const bf16x8*)(Ac + (wm + j * 16 + l16) * 64 +
                                                ((s * 4 + quad) ^ (l16 & 7)) * 8);
#pragma unroll
            for (int ft = 0; ft < 3; ++ft)
#pragma unroll
                for (int s = 0; s < 2; ++s)
                    bfr[ft][s] = *(const bf16x8*)(Bc + (wn + ft * 16 + l16) * 64 +
                                                  ((s * 4 + quad) ^ (l16 & 7)) * 8);
            if (kt < 15) { SA(nb, 1, kt + 1); SA(nb, 3, kt + 1); }
            __builtin_amdgcn_s_barrier();
            asm volatile("s_waitcnt lgkmcnt(0)" ::: "memory");
            __builtin_amdgcn_sched_barrier(0);
            __builtin_amdgcn_s_setprio(1);
#pragma unroll
            for (int ft = 0; ft < 3; ++ft)
#pragma unroll
                for (int j = 0; j < 2; ++j) {
                    acc[ft][j] = mfma32(bfr[ft][0], a0[j][0], acc[ft][j]);
                    acc[ft][j] = mfma32(bfr[ft][1], a0[j][1], acc[ft][j]);
                }
            __builtin_amdgcn_s_setprio(0);
            __builtin_amdgcn_s_barrier();
        }
        // ---------------- phases 1..3 ----------------
#pragma unroll
        for (int p = 1; p < 4; ++p) {
            bf16x8 a0[2][2];
#pragma unroll
            for (int j = 0; j < 2; ++j)
#pragma unroll
                for (int s = 0; s < 2; ++s)
                    a0[j][s] = *(const bf16x8*)(Ac + (wm + (p * 2 + j) * 16 + l16) * 64 +
                                                ((s * 4 + quad) ^ (l16 & 7)) * 8);
            if (kt < 14) {
                if (p == 1)      { SB(cur, 0, kt + 2); SB(cur, 1, kt + 2); }
                else if (p == 2) { SA(cur, 0, kt + 2); SA(cur, 2, kt + 2); }
                else             { SB(cur, 2, kt + 2); }
            }
            __builtin_amdgcn_s_barrier();
            asm volatile("s_waitcnt lgkmcnt(0)" ::: "memory");
            __builtin_amdgcn_sched_barrier(0);
            __builtin_amdgcn_s_setprio(1);
#pragma unroll
            for (int ft = 0; ft < 3; ++ft)
#pragma unroll
                for (int j = 0; j < 2; ++j) {
                    acc[ft][p * 2 + j] = mfma32(bfr[ft][0], a0[j][0], acc[ft][p * 2 + j]);
                    acc[ft][p * 2 + j] = mfma32(bfr[ft][1], a0[j][1], acc[ft][p * 2 + j]);
                }
            __builtin_amdgcn_s_setprio(0);
            if (p < 3) {
                __builtin_amdgcn_s_barrier();
            } else {
                if (kt < 14)       { asm volatile("s_waitcnt vmcnt(5)" ::: "memory"); }
                else if (kt == 14) { asm volatile("s_waitcnt vmcnt(0)" ::: "memory"); }
                if (kt < 15) __builtin_amdgcn_s_barrier();
            }
        }
    }
#undef SA
#undef SB

    // Epilogue: per-fragment Q/K/V routing. featg spans one matrix per fragment
    // (16-wide fragments; matrix boundaries are multiples of 16).
#pragma unroll
    for (int ft = 0; ft < 3; ++ft) {
        const int featg = blockIdx.y * 192 + wn + ft * 16 + quad * 4;
        const int mat = featg >> 10;           // 0=Q, 1=K, 2=V
        const int fin = featg & 1023;
        if (mat < 2) {
            // Q/K: [b,h,s,d]; lane owns 4 consecutive d -> 8B stores. Q gets QSCALE.
            const float* bp = (mat == 0) ? bq : bk;
            unsigned short* op = (mat == 0) ? Qo : Ko;
            const float sc = (mat == 0) ? QSCALE : 1.0f;
            const float4 b4 = *(const float4*)(bp + fin);
            const int h = fin >> 6, d = fin & 63;
#pragma unroll
            for (int st = 0; st < 8; ++st) {
                const int sg = blockIdx.x * 256 + wm + st * 16 + l16;
                const int b = sg >> 10, s = sg & 1023;
                ushortx4 o4;
                o4[0] = f2bf((acc[ft][st][0] + b4.x) * sc);
                o4[1] = f2bf((acc[ft][st][1] + b4.y) * sc);
                o4[2] = f2bf((acc[ft][st][2] + b4.z) * sc);
                o4[3] = f2bf((acc[ft][st][3] + b4.w) * sc);
                *(ushortx4*)(op + (((size_t)(b * 16 + h) * 1024 + s) * 64 + d)) = o4;
            }
        } else {
            // V: [b,h,d,s'] with per-64-window PV-fragment permutation:
            // s = 64a + nt*16 + q*4 + j -> s' = 64a + ((st>>1)&1)*32 + q*8 + (st&1)*4 + j
            const float4 b4 = *(const float4*)(bv + fin);
#pragma unroll
            for (int r = 0; r < 4; ++r) {
                const int fr = fin + r;
                const int h = fr >> 6, d = fr & 63;
                const float bias = (r == 0) ? b4.x : (r == 1) ? b4.y : (r == 2) ? b4.z : b4.w;
#pragma unroll
                for (int st = 0; st < 8; ++st) {
                    const int sg = blockIdx.x * 256 + wm + st * 16 + l16;
                    const int b = sg >> 10, s = sg & 1023;
                    const int sp = (s & ~63) + ((st >> 1) & 1) * 32 + (l16 >> 2) * 8 +
                                   (st & 1) * 4 + (l16 & 3);
                    Vo[((size_t)(b * 16 + h) * 64 + d) * 1024 + sp] = f2bf(acc[ft][st][r] + bias);
                }
            }
        }
    }
}

// ---------------- flash attention: 128-row Q tile, direct-global Q fragments ----------
// grid (128, 8): x = head (id%8 = head%8 -> one head per XCD), y = 128-row q-tile.
__global__ __launch_bounds__(256) void attn(
    const unsigned short* __restrict__ Q,   // [b,h,s,d] (scaled by 0.125*log2e)
    const unsigned short* __restrict__ Kg,  // [b,h,s,d]
    const unsigned short* __restrict__ Vt,  // [b,h,d,s'] (permuted)
    const float* __restrict__ mask,         // [B][S]
    unsigned short* __restrict__ ctx)       // [B,S,H] bf16
{
    __shared__ unsigned short Ks[64 * 64];
    __shared__ unsigned short Vs[64 * 64];
    __shared__ float Msall[1024];

    const int t = threadIdx.x;
    const int wave = t >> 6, lane = t & 63, quad = lane >> 4, l16 = lane & 15;
    const int s7 = l16 & 7;
    const int head = blockIdx.x;
    const int b = head >> 4, h = head & 15;
    const int q0 = blockIdx.y * 128;
    const unsigned short* Qh = Q + (size_t)head * 65536;
    const unsigned short* Kh = Kg + (size_t)head * 65536;
    const unsigned short* Vh = Vt + (size_t)head * 65536;

    const int srow = t >> 3;
    const int scol = ((t & 7) ^ (srow & 7)) * 8;

    {   // mask row -> LDS, pre-scaled by log2e
        float4 m4 = *(const float4*)(mask + b * 1024 + t * 4);
        m4.x *= LOG2E; m4.y *= LOG2E; m4.z *= LOG2E; m4.w *= LOG2E;
        *(float4*)(Msall + t * 4) = m4;
    }

    // Q fragments direct from global: qf[qg][s][j] = Q[q0+wave*32+qg*16+l16][s*32+quad*8+j]
    bf16x8 qf[2][2];
#pragma unroll
    for (int qg = 0; qg < 2; qg++) {
        const unsigned short* qp = Qh + (size_t)(q0 + wave * 32 + qg * 16 + l16) * 64 + quad * 8;
        qf[qg][0] = *(const bf16x8*)(qp);
        qf[qg][1] = *(const bf16x8*)(qp + 32);
    }

    float rs0 = 0.f, rs1 = 0.f;
    floatx4 o_acc[2][4] = {};   // [qg][dt]: O^T rows d = dt*16+quad*4+r, col q = l16

    for (int k0 = 0; k0 < 1024; k0 += 64) {
        __syncthreads();
#pragma unroll
        for (int i = 0; i < 2; i++) {
            ASYNC16(Kh + (size_t)(k0 + i * 32 + srow) * 64 + scol, Ks + i * 2048 + t * 8);
            ASYNC16(Vh + (size_t)(i * 32 + srow) * 1024 + k0 + scol, Vs + i * 2048 + t * 8);
        }
        __syncthreads();

        short4v pf0[4], pf1[4];
#pragma unroll
        for (int nt = 0; nt < 4; nt++) {
            int krow = nt * 16 + l16;
            bf16x8 kf0 = *(const bf16x8*)(Ks + krow * 64 + ((quad ^ s7) * 8));
            bf16x8 kf1 = *(const bf16x8*)(Ks + krow * 64 + (((4 + quad) ^ s7) * 8));
            floatx4 mk = *(const floatx4*)(Msall + k0 + nt * 16 + quad * 4);
            floatx4 z0 = {0.f, 0.f, 0.f, 0.f};
            z0 = mfma32(kf0, qf[0][0], z0);
            z0 = mfma32(kf1, qf[0][1], z0);
            floatx4 z1 = {0.f, 0.f, 0.f, 0.f};
            z1 = mfma32(kf0, qf[1][0], z1);
            z1 = mfma32(kf1, qf[1][1], z1);
#pragma unroll
            for (int r = 0; r < 4; r++) {
                float p0 = exp2f(z0[r] + mk[r]);
                float p1 = exp2f(z1[r] + mk[r]);
                rs0 += p0;
                rs1 += p1;
                pf0[nt][r] = (short)(__float_as_uint(p0) >> 16);
                pf1[nt][r] = (short)(__float_as_uint(p1) >> 16);
            }
        }

        // O^T += V^T P^T; Vs permuted so (nt,nt+1) fragments are one b128 read.
#pragma unroll
        for (int dt = 0; dt < 4; dt++) {
            int vrow = dt * 16 + l16;
            ushortx8 v01 = *(const ushortx8*)(Vs + vrow * 64 + ((quad ^ s7) * 8));
            ushortx8 v23 = *(const ushortx8*)(Vs + vrow * 64 + (((4 + quad) ^ s7) * 8));
            short4v vf0 = {(short)v01[0], (short)v01[1], (short)v01[2], (short)v01[3]};
            short4v vf1 = {(short)v01[4], (short)v01[5], (short)v01[6], (short)v01[7]};
            short4v vf2 = {(short)v23[0], (short)v23[1], (short)v23[2], (short)v23[3]};
            short4v vf3 = {(short)v23[4], (short)v23[5], (short)v23[6], (short)v23[7]};
            o_acc[0][dt] = mfma16(vf0, pf0[0], o_acc[0][dt]);
            o_acc[0][dt] = mfma16(vf1, pf0[1], o_acc[0][dt]);
            o_acc[0][dt] = mfma16(vf2, pf0[2], o_acc[0][dt]);
            o_acc[0][dt] = mfma16(vf3, pf0[3], o_acc[0][dt]);
            o_acc[1][dt] = mfma16(vf0, pf1[0], o_acc[1][dt]);
            o_acc[1][dt] = mfma16(vf1, pf1[1], o_acc[1][dt]);
            o_acc[1][dt] = mfma16(vf2, pf1[2], o_acc[1][dt]);
            o_acc[1][dt] = mfma16(vf3, pf1[3], o_acc[1][dt]);
        }
    }

#pragma unroll
    for (int qg = 0; qg < 2; qg++) {
        float v = (qg == 0) ? rs0 : rs1;
        v += __shfl_xor(v, 16);
        v += __shfl_xor(v, 32);
        float inv_l = 1.0f / v;
        int qrow = q0 + wave * 32 + qg * 16 + l16;
#pragma unroll
        for (int dt = 0; dt < 4; dt++) {
            ushortx4 o4;
#pragma unroll
            for (int r = 0; r < 4; r++) o4[r] = f2bf(o_acc[qg][dt][r] * inv_l);
            *(ushortx4*)(ctx + ((size_t)(b * 1024 + qrow)) * 1024 + h * 64 + dt * 16 + quad * 4) = o4;
        }
    }
}

// ---------------- out-proj GEMM + bias + bf16 residual -> x (bf16) ----------------
__global__ __launch_bounds__(256) void gemm_proj(
    const unsigned short* __restrict__ A,   // ctx bf16 [8192][1024]
    const unsigned short* __restrict__ W,   // Wo bf16 [1024][1024]
    const float* __restrict__ bo,
    const unsigned short* __restrict__ resid,  // hid_bf [8192][1024]
    unsigned short* __restrict__ X)         // bf16 [8192][1024]
{
    __shared__ unsigned short As[128 * 64];
    __shared__ unsigned short Bs[128 * 64];
    const int t = threadIdx.x;
    const int wave = t >> 6, lane = t & 63;
    const int quad = lane >> 4, l16 = lane & 15;
    const int wm = (wave >> 1) * 64, wn = (wave & 1) * 64;
    const int srow = t >> 3;
    const int scol = ((t & 7) ^ (srow & 7)) * 8;

    const unsigned short* Ag = A + ((size_t)blockIdx.x * 128 + srow) * 1024 + scol;
    const unsigned short* Wg = W + ((size_t)blockIdx.y * 128 + srow) * 1024 + scol;

    floatx4 acc[4][4] = {};
    kloop_bk64<false>(Ag, Wg, As, Bs, wm, wn, l16, quad, t, acc);

#pragma unroll
    for (int nt = 0; nt < 4; nt++) {
        int gn = blockIdx.y * 128 + wn + nt * 16 + l16;
        float bias = bo[gn];
#pragma unroll
        for (int mt = 0; mt < 4; mt++) {
#pragma unroll
            for (int r = 0; r < 4; r++) {
                int gm = blockIdx.x * 128 + wm + mt * 16 + quad * 4 + r;
                size_t off = (size_t)gm * 1024 + gn;
                X[off] = f2bf(acc[mt][nt][r] + bias + bf2f(resid[off]));
            }
        }
    }
}

// ---------------- LayerNorm: one block per token row (bf16 in, fp32 out) ------------
__global__ __launch_bounds__(256) void ln_k(const unsigned short* __restrict__ X,
                                            const float* __restrict__ g,
                                            const float* __restrict__ be,
                                            float* __restrict__ out)
{
    int row = blockIdx.x;
    int t = threadIdx.x;
    const unsigned short* xr = X + (size_t)row * 1024;
    ushortx4 xb = *(const ushortx4*)(xr + t * 4);
    float4 v;
    v.x = bf2f(xb[0]);
    v.y = bf2f(xb[1]);
    v.z = bf2f(xb[2]);
    v.w = bf2f(xb[3]);
    float s = v.x + v.y + v.z + v.w;
    float ss = v.x * v.x + v.y * v.y + v.z * v.z + v.w * v.w;
    for (int off = 1; off < 64; off <<= 1) {
        s += __shfl_xor(s, off);
        ss += __shfl_xor(ss, off);
    }
    __shared__ float red[8];
    int wave = t >> 6, lane = t & 63;
    if (lane == 0) { red[wave] = s; red[4 + wave] = ss; }
    __syncthreads();
    s = red[0] + red[1] + red[2] + red[3];
    ss = red[4] + red[5] + red[6] + red[7];
    float mu = s * (1.f / 1024.f);
    float var = ss * (1.f / 1024.f) - mu * mu;
    float inv = rsqrtf(var + 1e-12f);
    float4 gv = *(const float4*)(g + t * 4);
    float4 bv = *(const float4*)(be + t * 4);
    float4 o;
    o.x = (v.x - mu) * inv * gv.x + bv.x;
    o.y = (v.y - mu) * inv * gv.y + bv.y;
    o.z = (v.z - mu) * inv * gv.z + bv.z;
    o.w = (v.w - mu) * inv * gv.w + bv.w;
    *(float4*)(out + (size_t)row * 1024 + t * 4) = o;
}

extern "C" void kernel_launch(void* const* d_in, const int* in_sizes, int n_in,
                              void* d_out, int out_size, void* d_ws, size_t ws_size,
                              hipStream_t stream)
{
    const float* hidden = (const float*)d_in[0];
    const float* mask   = (const float*)d_in[1];
    const float* Wq = (const float*)d_in[2];
    const float* bq = (const float*)d_in[3];
    const float* Wk = (const float*)d_in[4];
    const float* bk = (const float*)d_in[5];
    const float* Wv = (const float*)d_in[6];
    const float* bv = (const float*)d_in[7];
    const float* Wo = (const float*)d_in[8];
    const float* bo = (const float*)d_in[9];
    const float* gamma = (const float*)d_in[10];
    const float* beta  = (const float*)d_in[11];
    float* out = (float*)d_out;

    char* ws = (char*)d_ws;
    // layout (bytes): hid_bf 16M | wqkv_bf 6M | wo_bf 2M | vt_bf 16M | ctx_bf 16M | q_bf 16M | k_bf 16M
    // x (bf16, 16M) aliases q_bf (dead after attn). total 88M.
    unsigned short* hid_bf  = (unsigned short*)(ws + 0);
    unsigned short* wqkv_bf = (unsigned short*)(ws + 16777216);
    unsigned short* wo_bf   = (unsigned short*)(ws + 23068672);
    unsigned short* vt_bf   = (unsigned short*)(ws + 25165824);
    unsigned short* ctx_bf  = (unsigned short*)(ws + 41943040);
    unsigned short* q_bf    = (unsigned short*)(ws + 58720256);
    unsigned short* k_bf    = (unsigned short*)(ws + 75497472);
    unsigned short* x_bf    = (unsigned short*)(ws + 58720256);

    cvt_all<<<6144, 256, 0, stream>>>(hidden, Wq, Wk, Wv, Wo, hid_bf, wqkv_bf, wo_bf);

    gemm_qkv<<<dim3(32, 16), 512, 0, stream>>>(hid_bf, wqkv_bf, bq, bk, bv, q_bf, k_bf, vt_bf);
    attn<<<dim3(128, 8), 256, 0, stream>>>(q_bf, k_bf, vt_bf, mask, ctx_bf);
    gemm_proj<<<dim3(64, 8), 256, 0, stream>>>(ctx_bf, wo_bf, bo, hid_bf, x_bf);
    ln_k<<<8192, 256, 0, stream>>>(x_bf, gamma, beta, out);
}

// Round 4
// 265.759 us; speedup vs baseline: 1.0328x; 1.0119x over previous
//
#include <hip/hip_runtime.h>
#include <stdint.h>

// B=8, S=1024, H=1024, NH=16, HD=64
typedef __attribute__((ext_vector_type(8))) __bf16 bf16x8;
typedef __attribute__((ext_vector_type(8))) unsigned short ushortx8;
typedef __attribute__((ext_vector_type(4))) unsigned short ushortx4;
typedef __attribute__((ext_vector_type(4))) short short4v;
typedef __attribute__((ext_vector_type(4))) float floatx4;

#define LOG2E 1.4426950408889634f
#define QSCALE 0.18033688011112043f   // 0.125 * log2e

#define ASYNC16(g, l) __builtin_amdgcn_global_load_lds( \
    (__attribute__((address_space(1))) void*)(g),       \
    (__attribute__((address_space(3))) void*)(l), 16, 0, 0)

__device__ __forceinline__ unsigned short f2bf(float f) {
    unsigned int u = __float_as_uint(f);
    u += 0x7fffu + ((u >> 16) & 1u);   // round-to-nearest-even
    return (unsigned short)(u >> 16);
}
__device__ __forceinline__ float bf2f(unsigned short u) {
    return __uint_as_float((unsigned)u << 16);
}

__device__ __forceinline__ floatx4 mfma32(bf16x8 a, bf16x8 b, floatx4 c) {
    return __builtin_amdgcn_mfma_f32_16x16x32_bf16(a, b, c, 0, 0, 0);
}
__device__ __forceinline__ floatx4 mfma16(short4v a, short4v b, floatx4 c) {
    return __builtin_amdgcn_mfma_f32_16x16x16bf16_1k(a, b, c, 0, 0, 0);
}

// ---------------- fp32 -> bf16 converts (hidden + all 4 weights, one launch) --------
__global__ __launch_bounds__(256) void cvt_all(
    const float* __restrict__ hidden,
    const float* __restrict__ Wq, const float* __restrict__ Wk,
    const float* __restrict__ Wv, const float* __restrict__ Wo,
    unsigned short* __restrict__ hid_bf,
    unsigned short* __restrict__ oqkv, unsigned short* __restrict__ oo)
{
    const float* src;
    unsigned short* dst;
    int i;
    if (blockIdx.x < 4096) {
        src = hidden; dst = hid_bf;
        i = blockIdx.x * 256 + threadIdx.x;          // < 1048576
    } else {
        int blk = (blockIdx.x - 4096) >> 9;
        src = (blk == 0) ? Wq : (blk == 1) ? Wk : (blk == 2) ? Wv : Wo;
        dst = (blk == 3) ? oo : oqkv + (size_t)blk * 1048576;
        i = ((blockIdx.x - 4096) & 511) * 256 + threadIdx.x;   // < 131072
    }
    const float4* p = (const float4*)src + (size_t)i * 2;
    float4 a = p[0], b = p[1];
    ushortx8 o;
    o[0] = f2bf(a.x); o[1] = f2bf(a.y); o[2] = f2bf(a.z); o[3] = f2bf(a.w);
    o[4] = f2bf(b.x); o[5] = f2bf(b.y); o[6] = f2bf(b.z); o[7] = f2bf(b.w);
    *((ushortx8*)dst + i) = o;
}

// ---------- shared BK=64 K-loop, 128x128 tile, swizzled LDS (used by gemm_proj) ----
template<bool SWAP>
__device__ __forceinline__ void kloop_bk64(
    const unsigned short* __restrict__ Ag,
    const unsigned short* __restrict__ Wg,
    unsigned short* As, unsigned short* Bs,
    int wm, int wn, int l16, int quad, int t,
    floatx4 acc[4][4])
{
#pragma unroll 1
    for (int k0 = 0; k0 < 1024; k0 += 64) {
        __syncthreads();
#pragma unroll
        for (int i = 0; i < 4; i++) {
            ASYNC16(Ag + (size_t)i * 32 * 1024 + k0, As + i * 2048 + t * 8);
            ASYNC16(Wg + (size_t)i * 32 * 1024 + k0, Bs + i * 2048 + t * 8);
        }
        __syncthreads();
#pragma unroll
        for (int s = 0; s < 2; s++) {
            int pb = ((s * 4 + quad) ^ (l16 & 7)) * 8;
            bf16x8 af[4], bfr[4];
#pragma unroll
            for (int mt = 0; mt < 4; mt++)
                af[mt] = *(const bf16x8*)(As + (wm + mt * 16 + l16) * 64 + pb);
#pragma unroll
            for (int nt = 0; nt < 4; nt++)
                bfr[nt] = *(const bf16x8*)(Bs + (wn + nt * 16 + l16) * 64 + pb);
            if (SWAP) {
#pragma unroll
                for (int ft = 0; ft < 4; ft++)
#pragma unroll
                    for (int st = 0; st < 4; st++)
                        acc[ft][st] = mfma32(bfr[ft], af[st], acc[ft][st]);
            } else {
#pragma unroll
                for (int mt = 0; mt < 4; mt++)
#pragma unroll
                    for (int nt = 0; nt < 4; nt++)
                        acc[mt][nt] = mfma32(af[mt], bfr[nt], acc[mt][nt]);
            }
        }
    }
}

// ---------------- merged QKV GEMM: 256x192 tile, 8-wave, 2-phase pipelined K-loop ---
// grid (32, 16) = 512 blocks, 512 threads, 1 block/CU (112 KiB LDS) = 2 balanced
// rounds. Round-1/2 A/B showed per-block time invariant to MFMA count at 4
// phases/K-tile (64 phases x ~900cyc overhead dominates) -> merge to 2 phases/K-tile
// (32 phases, 24 MFMA each), halving barrier/lgkm-drain events.
//
// LDS: 2 dbuf x (256x64 A + 192x64 B). Staging unit = 64 rows x 64 cols (8 KB = 1
// global_load_lds_dwordx4/thread), linear LDS dest + pre-swizzled global source.
// Per tile 7 units: A0..A3, B0..B2.
//   phase A (st 0..3): reads A rows wm+0..63 (units 0/2 per wave) + ALL B -> regs;
//                      issues A1,A3 of kt+1 into nb (units 1/3: last read in prev
//                      tile's phase B, tile-end barrier protects).
//   phase B (st 4..7): reads A rows wm+64..127 (units 1/3);
//                      issues B0,B1,B2,A0,A2 of kt+2 into cur (B reg-cached since
//                      phase A; A units 0/2 last read in phase A; phase-A end
//                      barrier protects).
// Ledger: entering tile kt, <=5 outstanding (kt+1's B0,B1,B2,A0,A2). Tile issues
// +2 (phA) +5 (phB) = 12; tile-end vmcnt(5) keeps the 5 youngest (kt+2's) and
// proves all of kt+1 landed. Drain vmcnt(0) only at kt==14.
__global__ __launch_bounds__(512, 2) void gemm_qkv(
    const unsigned short* __restrict__ A,   // [8192][1024] bf16
    const unsigned short* __restrict__ W,   // [Wq;Wk;Wv] [3072][1024]
    const float* __restrict__ bq, const float* __restrict__ bk, const float* __restrict__ bv,
    unsigned short* __restrict__ Qo, unsigned short* __restrict__ Ko,
    unsigned short* __restrict__ Vo)
{
    __shared__ unsigned short As[2][16384];   // [buf][256*64]
    __shared__ unsigned short Bs[2][12288];   // [buf][192*64]
    const int t = threadIdx.x;
    const int lane = t & 63, quad = lane >> 4, l16 = lane & 15;
    const int wid = t >> 6;
    const int wm = (wid >> 2) * 128;   // seq offset of wave within tile
    const int wn = (wid & 3) * 48;     // feature offset of wave within tile
    const int rr = t >> 3;             // staging row within 64-row unit
    const int cc = ((t & 7) ^ (rr & 7)) * 8;   // pre-swizzled global col (elements)
    const int t8 = t * 8;              // linear LDS ushort offset within unit

    const unsigned short* Ab = A + ((size_t)blockIdx.x * 256 + rr) * 1024 + cc;
    const unsigned short* Wb = W + ((size_t)blockIdx.y * 192 + rr) * 1024 + cc;

#define SA(bf_, u_, kt_) ASYNC16(Ab + (size_t)(u_) * 65536 + (kt_) * 64, &As[bf_][(u_) * 4096 + t8])
#define SB(bf_, u_, kt_) ASYNC16(Wb + (size_t)(u_) * 65536 + (kt_) * 64, &Bs[bf_][(u_) * 4096 + t8])

    // prologue: tile0 complete (7 units), tile1 partial (B0,B1,B2,A0,A2)
    SA(0, 0, 0); SA(0, 1, 0); SA(0, 2, 0); SA(0, 3, 0);
    SB(0, 0, 0); SB(0, 1, 0); SB(0, 2, 0);
    SB(1, 0, 1); SB(1, 1, 1); SB(1, 2, 1); SA(1, 0, 1); SA(1, 2, 1);
    asm volatile("s_waitcnt vmcnt(5)" ::: "memory");   // tile0 landed, tile1's 5 in flight
    __builtin_amdgcn_s_barrier();

    floatx4 acc[3][8] = {};   // [ft][st]

#pragma unroll 1
    for (int kt = 0; kt < 16; ++kt) {
        const int cur = kt & 1, nb = cur ^ 1;
        const unsigned short* Ac = As[cur];
        const unsigned short* Bc = Bs[cur];
        bf16x8 bfr[3][2];
        bf16x8 af[4][2];

        // ---------------- phase A: st 0..3 + all B frags ----------------
#pragma unroll
        for (int j = 0; j < 4; ++j)
#pragma unroll
            for (int s = 0; s < 2; ++s)
                af[j][s] = *(const bf16x8*)(Ac + (wm + j * 16 + l16) * 64 +
                                            ((s * 4 + quad) ^ (l16 & 7)) * 8);
#pragma unroll
        for (int ft = 0; ft < 3; ++ft)
#pragma unroll
            for (int s = 0; s < 2; ++s)
                bfr[ft][s] = *(const bf16x8*)(Bc + (wn + ft * 16 + l16) * 64 +
                                              ((s * 4 + quad) ^ (l16 & 7)) * 8);
        if (kt < 15) { SA(nb, 1, kt + 1); SA(nb, 3, kt + 1); }
        __builtin_amdgcn_s_barrier();
        asm volatile("s_waitcnt lgkmcnt(0)" ::: "memory");
        __builtin_amdgcn_sched_barrier(0);
        __builtin_amdgcn_s_setprio(1);
#pragma unroll
        for (int ft = 0; ft < 3; ++ft)
#pragma unroll
            for (int j = 0; j < 4; ++j) {
                acc[ft][j] = mfma32(bfr[ft][0], af[j][0], acc[ft][j]);
                acc[ft][j] = mfma32(bfr[ft][1], af[j][1], acc[ft][j]);
            }
        __builtin_amdgcn_s_setprio(0);
        __builtin_amdgcn_s_barrier();

        // ---------------- phase B: st 4..7 ----------------
#pragma unroll
        for (int j = 0; j < 4; ++j)
#pragma unroll
            for (int s = 0; s < 2; ++s)
                af[j][s] = *(const bf16x8*)(Ac + (wm + 64 + j * 16 + l16) * 64 +
                                            ((s * 4 + quad) ^ (l16 & 7)) * 8);
        if (kt < 14) {
            SB(cur, 0, kt + 2); SB(cur, 1, kt + 2); SB(cur, 2, kt + 2);
            SA(cur, 0, kt + 2); SA(cur, 2, kt + 2);
        }
        __builtin_amdgcn_s_barrier();
        asm volatile("s_waitcnt lgkmcnt(0)" ::: "memory");
        __builtin_amdgcn_sched_barrier(0);
        __builtin_amdgcn_s_setprio(1);
#pragma unroll
        for (int ft = 0; ft < 3; ++ft)
#pragma unroll
            for (int j = 0; j < 4; ++j) {
                acc[ft][4 + j] = mfma32(bfr[ft][0], af[j][0], acc[ft][4 + j]);
                acc[ft][4 + j] = mfma32(bfr[ft][1], af[j][1], acc[ft][4 + j]);
            }
        __builtin_amdgcn_s_setprio(0);
        if (kt < 14)       { asm volatile("s_waitcnt vmcnt(5)" ::: "memory"); }
        else if (kt == 14) { asm volatile("s_waitcnt vmcnt(0)" ::: "memory"); }
        if (kt < 15) __builtin_amdgcn_s_barrier();
    }
#undef SA
#undef SB

    // Epilogue: per-fragment Q/K/V routing. featg spans one matrix per fragment
    // (16-wide fragments; matrix boundaries are multiples of 16).
#pragma unroll
    for (int ft = 0; ft < 3; ++ft) {
        const int featg = blockIdx.y * 192 + wn + ft * 16 + quad * 4;
        const int mat = featg >> 10;           // 0=Q, 1=K, 2=V
        const int fin = featg & 1023;
        if (mat < 2) {
            // Q/K: [b,h,s,d]; lane owns 4 consecutive d -> 8B stores. Q gets QSCALE.
            const float* bp = (mat == 0) ? bq : bk;
            unsigned short* op = (mat == 0) ? Qo : Ko;
            const float sc = (mat == 0) ? QSCALE : 1.0f;
            const float4 b4 = *(const float4*)(bp + fin);
            const int h = fin >> 6, d = fin & 63;
#pragma unroll
            for (int st = 0; st < 8; ++st) {
                const int sg = blockIdx.x * 256 + wm + st * 16 + l16;
                const int b = sg >> 10, s = sg & 1023;
                ushortx4 o4;
                o4[0] = f2bf((acc[ft][st][0] + b4.x) * sc);
                o4[1] = f2bf((acc[ft][st][1] + b4.y) * sc);
                o4[2] = f2bf((acc[ft][st][2] + b4.z) * sc);
                o4[3] = f2bf((acc[ft][st][3] + b4.w) * sc);
                *(ushortx4*)(op + (((size_t)(b * 16 + h) * 1024 + s) * 64 + d)) = o4;
            }
        } else {
            // V: [b,h,d,s'] with per-64-window PV-fragment permutation:
            // s = 64a + nt*16 + q*4 + j -> s' = 64a + ((st>>1)&1)*32 + q*8 + (st&1)*4 + j
            const float4 b4 = *(const float4*)(bv + fin);
#pragma unroll
            for (int r = 0; r < 4; ++r) {
                const int fr = fin + r;
                const int h = fr >> 6, d = fr & 63;
                const float bias = (r == 0) ? b4.x : (r == 1) ? b4.y : (r == 2) ? b4.z : b4.w;
#pragma unroll
                for (int st = 0; st < 8; ++st) {
                    const int sg = blockIdx.x * 256 + wm + st * 16 + l16;
                    const int b = sg >> 10, s = sg & 1023;
                    const int sp = (s & ~63) + ((st >> 1) & 1) * 32 + (l16 >> 2) * 8 +
                                   (st & 1) * 4 + (l16 & 3);
                    Vo[((size_t)(b * 16 + h) * 64 + d) * 1024 + sp] = f2bf(acc[ft][st][r] + bias);
                }
            }
        }
    }
}

// ---------------- flash attention: 128-row Q tile, direct-global Q fragments ----------
// grid (128, 8): x = head (id%8 = head%8 -> one head per XCD), y = 128-row q-tile.
__global__ __launch_bounds__(256) void attn(
    const unsigned short* __restrict__ Q,   // [b,h,s,d] (scaled by 0.125*log2e)
    const unsigned short* __restrict__ Kg,  // [b,h,s,d]
    const unsigned short* __restrict__ Vt,  // [b,h,d,s'] (permuted)
    const float* __restrict__ mask,         // [B][S]
    unsigned short* __restrict__ ctx)       // [B,S,H] bf16
{
    __shared__ unsigned short Ks[64 * 64];
    __shared__ unsigned short Vs[64 * 64];
    __shared__ float Msall[1024];

    const int t = threadIdx.x;
    const int wave = t >> 6, lane = t & 63, quad = lane >> 4, l16 = lane & 15;
    const int s7 = l16 & 7;
    const int head = blockIdx.x;
    const int b = head >> 4, h = head & 15;
    const int q0 = blockIdx.y * 128;
    const unsigned short* Qh = Q + (size_t)head * 65536;
    const unsigned short* Kh = Kg + (size_t)head * 65536;
    const unsigned short* Vh = Vt + (size_t)head * 65536;

    const int srow = t >> 3;
    const int scol = ((t & 7) ^ (srow & 7)) * 8;

    {   // mask row -> LDS, pre-scaled by log2e
        float4 m4 = *(const float4*)(mask + b * 1024 + t * 4);
        m4.x *= LOG2E; m4.y *= LOG2E; m4.z *= LOG2E; m4.w *= LOG2E;
        *(float4*)(Msall + t * 4) = m4;
    }

    // Q fragments direct from global: qf[qg][s][j] = Q[q0+wave*32+qg*16+l16][s*32+quad*8+j]
    bf16x8 qf[2][2];
#pragma unroll
    for (int qg = 0; qg < 2; qg++) {
        const unsigned short* qp = Qh + (size_t)(q0 + wave * 32 + qg * 16 + l16) * 64 + quad * 8;
        qf[qg][0] = *(const bf16x8*)(qp);
        qf[qg][1] = *(const bf16x8*)(qp + 32);
    }

    float rs0 = 0.f, rs1 = 0.f;
    floatx4 o_acc[2][4] = {};   // [qg][dt]: O^T rows d = dt*16+quad*4+r, col q = l16

    for (int k0 = 0; k0 < 1024; k0 += 64) {
        __syncthreads();
#pragma unroll
        for (int i = 0; i < 2; i++) {
            ASYNC16(Kh + (size_t)(k0 + i * 32 + srow) * 64 + scol, Ks + i * 2048 + t * 8);
            ASYNC16(Vh + (size_t)(i * 32 + srow) * 1024 + k0 + scol, Vs + i * 2048 + t * 8);
        }
        __syncthreads();

        short4v pf0[4], pf1[4];
#pragma unroll
        for (int nt = 0; nt < 4; nt++) {
            int krow = nt * 16 + l16;
            bf16x8 kf0 = *(const bf16x8*)(Ks + krow * 64 + ((quad ^ s7) * 8));
            bf16x8 kf1 = *(const bf16x8*)(Ks + krow * 64 + (((4 + quad) ^ s7) * 8));
            floatx4 mk = *(const floatx4*)(Msall + k0 + nt * 16 + quad * 4);
            floatx4 z0 = {0.f, 0.f, 0.f, 0.f};
            z0 = mfma32(kf0, qf[0][0], z0);
            z0 = mfma32(kf1, qf[0][1], z0);
            floatx4 z1 = {0.f, 0.f, 0.f, 0.f};
            z1 = mfma32(kf0, qf[1][0], z1);
            z1 = mfma32(kf1, qf[1][1], z1);
#pragma unroll
            for (int r = 0; r < 4; r++) {
                float p0 = exp2f(z0[r] + mk[r]);
                float p1 = exp2f(z1[r] + mk[r]);
                rs0 += p0;
                rs1 += p1;
                pf0[nt][r] = (short)(__float_as_uint(p0) >> 16);
                pf1[nt][r] = (short)(__float_as_uint(p1) >> 16);
            }
        }

        // O^T += V^T P^T; Vs permuted so (nt,nt+1) fragments are one b128 read.
#pragma unroll
        for (int dt = 0; dt < 4; dt++) {
            int vrow = dt * 16 + l16;
            ushortx8 v01 = *(const ushortx8*)(Vs + vrow * 64 + ((quad ^ s7) * 8));
            ushortx8 v23 = *(const ushortx8*)(Vs + vrow * 64 + (((4 + quad) ^ s7) * 8));
            short4v vf0 = {(short)v01[0], (short)v01[1], (short)v01[2], (short)v01[3]};
            short4v vf1 = {(short)v01[4], (short)v01[5], (short)v01[6], (short)v01[7]};
            short4v vf2 = {(short)v23[0], (short)v23[1], (short)v23[2], (short)v23[3]};
            short4v vf3 = {(short)v23[4], (short)v23[5], (short)v23[6], (short)v23[7]};
            o_acc[0][dt] = mfma16(vf0, pf0[0], o_acc[0][dt]);
            o_acc[0][dt] = mfma16(vf1, pf0[1], o_acc[0][dt]);
            o_acc[0][dt] = mfma16(vf2, pf0[2], o_acc[0][dt]);
            o_acc[0][dt] = mfma16(vf3, pf0[3], o_acc[0][dt]);
            o_acc[1][dt] = mfma16(vf0, pf1[0], o_acc[1][dt]);
            o_acc[1][dt] = mfma16(vf1, pf1[1], o_acc[1][dt]);
            o_acc[1][dt] = mfma16(vf2, pf1[2], o_acc[1][dt]);
            o_acc[1][dt] = mfma16(vf3, pf1[3], o_acc[1][dt]);
        }
    }

#pragma unroll
    for (int qg = 0; qg < 2; qg++) {
        float v = (qg == 0) ? rs0 : rs1;
        v += __shfl_xor(v, 16);
        v += __shfl_xor(v, 32);
        float inv_l = 1.0f / v;
        int qrow = q0 + wave * 32 + qg * 16 + l16;
#pragma unroll
        for (int dt = 0; dt < 4; dt++) {
            ushortx4 o4;
#pragma unroll
            for (int r = 0; r < 4; r++) o4[r] = f2bf(o_acc[qg][dt][r] * inv_l);
            *(ushortx4*)(ctx + ((size_t)(b * 1024 + qrow)) * 1024 + h * 64 + dt * 16 + quad * 4) = o4;
        }
    }
}

// ---------------- out-proj GEMM + bias + bf16 residual -> x (bf16) ----------------
__global__ __launch_bounds__(256) void gemm_proj(
    const unsigned short* __restrict__ A,   // ctx bf16 [8192][1024]
    const unsigned short* __restrict__ W,   // Wo bf16 [1024][1024]
    const float* __restrict__ bo,
    const unsigned short* __restrict__ resid,  // hid_bf [8192][1024]
    unsigned short* __restrict__ X)         // bf16 [8192][1024]
{
    __shared__ unsigned short As[128 * 64];
    __shared__ unsigned short Bs[128 * 64];
    const int t = threadIdx.x;
    const int wave = t >> 6, lane = t & 63;
    const int quad = lane >> 4, l16 = lane & 15;
    const int wm = (wave >> 1) * 64, wn = (wave & 1) * 64;
    const int srow = t >> 3;
    const int scol = ((t & 7) ^ (srow & 7)) * 8;

    const unsigned short* Ag = A + ((size_t)blockIdx.x * 128 + srow) * 1024 + scol;
    const unsigned short* Wg = W + ((size_t)blockIdx.y * 128 + srow) * 1024 + scol;

    floatx4 acc[4][4] = {};
    kloop_bk64<false>(Ag, Wg, As, Bs, wm, wn, l16, quad, t, acc);

#pragma unroll
    for (int nt = 0; nt < 4; nt++) {
        int gn = blockIdx.y * 128 + wn + nt * 16 + l16;
        float bias = bo[gn];
#pragma unroll
        for (int mt = 0; mt < 4; mt++) {
#pragma unroll
            for (int r = 0; r < 4; r++) {
                int gm = blockIdx.x * 128 + wm + mt * 16 + quad * 4 + r;
                size_t off = (size_t)gm * 1024 + gn;
                X[off] = f2bf(acc[mt][nt][r] + bias + bf2f(resid[off]));
            }
        }
    }
}

// ---------------- LayerNorm: one block per token row (bf16 in, fp32 out) ------------
__global__ __launch_bounds__(256) void ln_k(const unsigned short* __restrict__ X,
                                            const float* __restrict__ g,
                                            const float* __restrict__ be,
                                            float* __restrict__ out)
{
    int row = blockIdx.x;
    int t = threadIdx.x;
    const unsigned short* xr = X + (size_t)row * 1024;
    ushortx4 xb = *(const ushortx4*)(xr + t * 4);
    float4 v;
    v.x = bf2f(xb[0]);
    v.y = bf2f(xb[1]);
    v.z = bf2f(xb[2]);
    v.w = bf2f(xb[3]);
    float s = v.x + v.y + v.z + v.w;
    float ss = v.x * v.x + v.y * v.y + v.z * v.z + v.w * v.w;
    for (int off = 1; off < 64; off <<= 1) {
        s += __shfl_xor(s, off);
        ss += __shfl_xor(ss, off);
    }
    __shared__ float red[8];
    int wave = t >> 6, lane = t & 63;
    if (lane == 0) { red[wave] = s; red[4 + wave] = ss; }
    __syncthreads();
    s = red[0] + red[1] + red[2] + red[3];
    ss = red[4] + red[5] + red[6] + red[7];
    float mu = s * (1.f / 1024.f);
    float var = ss * (1.f / 1024.f) - mu * mu;
    float inv = rsqrtf(var + 1e-12f);
    float4 gv = *(const float4*)(g + t * 4);
    float4 bv = *(const float4*)(be + t * 4);
    float4 o;
    o.x = (v.x - mu) * inv * gv.x + bv.x;
    o.y = (v.y - mu) * inv * gv.y + bv.y;
    o.z = (v.z - mu) * inv * gv.z + bv.z;
    o.w = (v.w - mu) * inv * gv.w + bv.w;
    *(float4*)(out + (size_t)row * 1024 + t * 4) = o;
}

extern "C" void kernel_launch(void* const* d_in, const int* in_sizes, int n_in,
                              void* d_out, int out_size, void* d_ws, size_t ws_size,
                              hipStream_t stream)
{
    const float* hidden = (const float*)d_in[0];
    const float* mask   = (const float*)d_in[1];
    const float* Wq = (const float*)d_in[2];
    const float* bq = (const float*)d_in[3];
    const float* Wk = (const float*)d_in[4];
    const float* bk = (const float*)d_in[5];
    const float* Wv = (const float*)d_in[6];
    const float* bv = (const float*)d_in[7];
    const float* Wo = (const float*)d_in[8];
    const float* bo = (const float*)d_in[9];
    const float* gamma = (const float*)d_in[10];
    const float* beta  = (const float*)d_in[11];
    float* out = (float*)d_out;

    char* ws = (char*)d_ws;
    // layout (bytes): hid_bf 16M | wqkv_bf 6M | wo_bf 2M | vt_bf 16M | ctx_bf 16M | q_bf 16M | k_bf 16M
    // x (bf16, 16M) aliases q_bf (dead after attn). total 88M.
    unsigned short* hid_bf  = (unsigned short*)(ws + 0);
    unsigned short* wqkv_bf = (unsigned short*)(ws + 16777216);
    unsigned short* wo_bf   = (unsigned short*)(ws + 23068672);
    unsigned short* vt_bf   = (unsigned short*)(ws + 25165824);
    unsigned short* ctx_bf  = (unsigned short*)(ws + 41943040);
    unsigned short* q_bf    = (unsigned short*)(ws + 58720256);
    unsigned short* k_bf    = (unsigned short*)(ws + 75497472);
    unsigned short* x_bf    = (unsigned short*)(ws + 58720256);

    cvt_all<<<6144, 256, 0, stream>>>(hidden, Wq, Wk, Wv, Wo, hid_bf, wqkv_bf, wo_bf);

    gemm_qkv<<<dim3(32, 16), 512, 0, stream>>>(hid_bf, wqkv_bf, bq, bk, bv, q_bf, k_bf, vt_bf);
    attn<<<dim3(128, 8), 256, 0, stream>>>(q_bf, k_bf, vt_bf, mask, ctx_bf);
    gemm_proj<<<dim3(64, 8), 256, 0, stream>>>(ctx_bf, wo_bf, bo, hid_bf, x_bf);
    ln_k<<<8192, 256, 0, stream>>>(x_bf, gamma, beta, out);
}

// Round 6
// 260.375 us; speedup vs baseline: 1.0541x; 1.0207x over previous
//
#include <hip/hip_runtime.h>
#include <stdint.h>

// B=8, S=1024, H=1024, NH=16, HD=64
typedef __attribute__((ext_vector_type(8))) __bf16 bf16x8;
typedef __attribute__((ext_vector_type(8))) unsigned short ushortx8;
typedef __attribute__((ext_vector_type(4))) unsigned short ushortx4;
typedef __attribute__((ext_vector_type(4))) short short4v;
typedef __attribute__((ext_vector_type(4))) float floatx4;

#define LOG2E 1.4426950408889634f
#define QSCALE 0.18033688011112043f   // 0.125 * log2e

#define ASYNC16(g, l) __builtin_amdgcn_global_load_lds( \
    (__attribute__((address_space(1))) void*)(g),       \
    (__attribute__((address_space(3))) void*)(l), 16, 0, 0)

__device__ __forceinline__ unsigned short f2bf(float f) {
    unsigned int u = __float_as_uint(f);
    u += 0x7fffu + ((u >> 16) & 1u);   // round-to-nearest-even
    return (unsigned short)(u >> 16);
}
__device__ __forceinline__ float bf2f(unsigned short u) {
    return __uint_as_float((unsigned)u << 16);
}

__device__ __forceinline__ floatx4 mfma32(bf16x8 a, bf16x8 b, floatx4 c) {
    return __builtin_amdgcn_mfma_f32_16x16x32_bf16(a, b, c, 0, 0, 0);
}
__device__ __forceinline__ floatx4 mfma16(short4v a, short4v b, floatx4 c) {
    return __builtin_amdgcn_mfma_f32_16x16x16bf16_1k(a, b, c, 0, 0, 0);
}

// ---------------- fp32 -> bf16 converts (hidden + all 4 weights, one launch) --------
__global__ __launch_bounds__(256) void cvt_all(
    const float* __restrict__ hidden,
    const float* __restrict__ Wq, const float* __restrict__ Wk,
    const float* __restrict__ Wv, const float* __restrict__ Wo,
    unsigned short* __restrict__ hid_bf,
    unsigned short* __restrict__ oqkv, unsigned short* __restrict__ oo)
{
    const float* src;
    unsigned short* dst;
    int i;
    if (blockIdx.x < 4096) {
        src = hidden; dst = hid_bf;
        i = blockIdx.x * 256 + threadIdx.x;          // < 1048576
    } else {
        int blk = (blockIdx.x - 4096) >> 9;
        src = (blk == 0) ? Wq : (blk == 1) ? Wk : (blk == 2) ? Wv : Wo;
        dst = (blk == 3) ? oo : oqkv + (size_t)blk * 1048576;
        i = ((blockIdx.x - 4096) & 511) * 256 + threadIdx.x;   // < 131072
    }
    const float4* p = (const float4*)src + (size_t)i * 2;
    float4 a = p[0], b = p[1];
    ushortx8 o;
    o[0] = f2bf(a.x); o[1] = f2bf(a.y); o[2] = f2bf(a.z); o[3] = f2bf(a.w);
    o[4] = f2bf(b.x); o[5] = f2bf(b.y); o[6] = f2bf(b.z); o[7] = f2bf(b.w);
    *((ushortx8*)dst + i) = o;
}

// ---------- shared BK=64 K-loop, 128x128 tile, swizzled LDS (used by gemm_proj) ----
template<bool SWAP>
__device__ __forceinline__ void kloop_bk64(
    const unsigned short* __restrict__ Ag,
    const unsigned short* __restrict__ Wg,
    unsigned short* As, unsigned short* Bs,
    int wm, int wn, int l16, int quad, int t,
    floatx4 acc[4][4])
{
#pragma unroll 1
    for (int k0 = 0; k0 < 1024; k0 += 64) {
        __syncthreads();
#pragma unroll
        for (int i = 0; i < 4; i++) {
            ASYNC16(Ag + (size_t)i * 32 * 1024 + k0, As + i * 2048 + t * 8);
            ASYNC16(Wg + (size_t)i * 32 * 1024 + k0, Bs + i * 2048 + t * 8);
        }
        __syncthreads();
#pragma unroll
        for (int s = 0; s < 2; s++) {
            int pb = ((s * 4 + quad) ^ (l16 & 7)) * 8;
            bf16x8 af[4], bfr[4];
#pragma unroll
            for (int mt = 0; mt < 4; mt++)
                af[mt] = *(const bf16x8*)(As + (wm + mt * 16 + l16) * 64 + pb);
#pragma unroll
            for (int nt = 0; nt < 4; nt++)
                bfr[nt] = *(const bf16x8*)(Bs + (wn + nt * 16 + l16) * 64 + pb);
            if (SWAP) {
#pragma unroll
                for (int ft = 0; ft < 4; ft++)
#pragma unroll
                    for (int st = 0; st < 4; st++)
                        acc[ft][st] = mfma32(bfr[ft], af[st], acc[ft][st]);
            } else {
#pragma unroll
                for (int mt = 0; mt < 4; mt++)
#pragma unroll
                    for (int nt = 0; nt < 4; nt++)
                        acc[mt][nt] = mfma32(af[mt], bfr[nt], acc[mt][nt]);
            }
        }
    }
}

// ---------------- merged QKV GEMM: 256x192 tile, 8-wave, 2-phase pipelined K-loop ---
// grid (32, 16) = 512 blocks, 512 threads, 1 block/CU (112 KiB LDS) = 2 balanced
// rounds. 2 phases/K-tile (32 phases, 24 MFMA each).
__global__ __launch_bounds__(512, 2) void gemm_qkv(
    const unsigned short* __restrict__ A,   // [8192][1024] bf16
    const unsigned short* __restrict__ W,   // [Wq;Wk;Wv] [3072][1024]
    const float* __restrict__ bq, const float* __restrict__ bk, const float* __restrict__ bv,
    unsigned short* __restrict__ Qo, unsigned short* __restrict__ Ko,
    unsigned short* __restrict__ Vo)
{
    __shared__ unsigned short As[2][16384];   // [buf][256*64]
    __shared__ unsigned short Bs[2][12288];   // [buf][192*64]
    const int t = threadIdx.x;
    const int lane = t & 63, quad = lane >> 4, l16 = lane & 15;
    const int wid = t >> 6;
    const int wm = (wid >> 2) * 128;   // seq offset of wave within tile
    const int wn = (wid & 3) * 48;     // feature offset of wave within tile
    const int rr = t >> 3;             // staging row within 64-row unit
    const int cc = ((t & 7) ^ (rr & 7)) * 8;   // pre-swizzled global col (elements)
    const int t8 = t * 8;              // linear LDS ushort offset within unit

    const unsigned short* Ab = A + ((size_t)blockIdx.x * 256 + rr) * 1024 + cc;
    const unsigned short* Wb = W + ((size_t)blockIdx.y * 192 + rr) * 1024 + cc;

#define SA(bf_, u_, kt_) ASYNC16(Ab + (size_t)(u_) * 65536 + (kt_) * 64, &As[bf_][(u_) * 4096 + t8])
#define SB(bf_, u_, kt_) ASYNC16(Wb + (size_t)(u_) * 65536 + (kt_) * 64, &Bs[bf_][(u_) * 4096 + t8])

    // prologue: tile0 complete (7 units), tile1 partial (B0,B1,B2,A0,A2)
    SA(0, 0, 0); SA(0, 1, 0); SA(0, 2, 0); SA(0, 3, 0);
    SB(0, 0, 0); SB(0, 1, 0); SB(0, 2, 0);
    SB(1, 0, 1); SB(1, 1, 1); SB(1, 2, 1); SA(1, 0, 1); SA(1, 2, 1);
    asm volatile("s_waitcnt vmcnt(5)" ::: "memory");   // tile0 landed, tile1's 5 in flight
    __builtin_amdgcn_s_barrier();

    floatx4 acc[3][8] = {};   // [ft][st]

#pragma unroll 1
    for (int kt = 0; kt < 16; ++kt) {
        const int cur = kt & 1, nb = cur ^ 1;
        const unsigned short* Ac = As[cur];
        const unsigned short* Bc = Bs[cur];
        bf16x8 bfr[3][2];
        bf16x8 af[4][2];

        // ---------------- phase A: st 0..3 + all B frags ----------------
#pragma unroll
        for (int j = 0; j < 4; ++j)
#pragma unroll
            for (int s = 0; s < 2; ++s)
                af[j][s] = *(const bf16x8*)(Ac + (wm + j * 16 + l16) * 64 +
                                            ((s * 4 + quad) ^ (l16 & 7)) * 8);
#pragma unroll
        for (int ft = 0; ft < 3; ++ft)
#pragma unroll
            for (int s = 0; s < 2; ++s)
                bfr[ft][s] = *(const bf16x8*)(Bc + (wn + ft * 16 + l16) * 64 +
                                              ((s * 4 + quad) ^ (l16 & 7)) * 8);
        if (kt < 15) { SA(nb, 1, kt + 1); SA(nb, 3, kt + 1); }
        __builtin_amdgcn_s_barrier();
        asm volatile("s_waitcnt lgkmcnt(0)" ::: "memory");
        __builtin_amdgcn_sched_barrier(0);
        __builtin_amdgcn_s_setprio(1);
#pragma unroll
        for (int ft = 0; ft < 3; ++ft)
#pragma unroll
            for (int j = 0; j < 4; ++j) {
                acc[ft][j] = mfma32(bfr[ft][0], af[j][0], acc[ft][j]);
                acc[ft][j] = mfma32(bfr[ft][1], af[j][1], acc[ft][j]);
            }
        __builtin_amdgcn_s_setprio(0);
        __builtin_amdgcn_s_barrier();

        // ---------------- phase B: st 4..7 ----------------
#pragma unroll
        for (int j = 0; j < 4; ++j)
#pragma unroll
            for (int s = 0; s < 2; ++s)
                af[j][s] = *(const bf16x8*)(Ac + (wm + 64 + j * 16 + l16) * 64 +
                                            ((s * 4 + quad) ^ (l16 & 7)) * 8);
        if (kt < 14) {
            SB(cur, 0, kt + 2); SB(cur, 1, kt + 2); SB(cur, 2, kt + 2);
            SA(cur, 0, kt + 2); SA(cur, 2, kt + 2);
        }
        __builtin_amdgcn_s_barrier();
        asm volatile("s_waitcnt lgkmcnt(0)" ::: "memory");
        __builtin_amdgcn_sched_barrier(0);
        __builtin_amdgcn_s_setprio(1);
#pragma unroll
        for (int ft = 0; ft < 3; ++ft)
#pragma unroll
            for (int j = 0; j < 4; ++j) {
                acc[ft][4 + j] = mfma32(bfr[ft][0], af[j][0], acc[ft][4 + j]);
                acc[ft][4 + j] = mfma32(bfr[ft][1], af[j][1], acc[ft][4 + j]);
            }
        __builtin_amdgcn_s_setprio(0);
        if (kt < 14)       { asm volatile("s_waitcnt vmcnt(5)" ::: "memory"); }
        else if (kt == 14) { asm volatile("s_waitcnt vmcnt(0)" ::: "memory"); }
        if (kt < 15) __builtin_amdgcn_s_barrier();
    }
#undef SA
#undef SB

    // Epilogue: per-fragment Q/K/V routing. featg spans one matrix per fragment
    // (16-wide fragments; matrix boundaries are multiples of 16).
#pragma unroll
    for (int ft = 0; ft < 3; ++ft) {
        const int featg = blockIdx.y * 192 + wn + ft * 16 + quad * 4;
        const int mat = featg >> 10;           // 0=Q, 1=K, 2=V
        const int fin = featg & 1023;
        if (mat < 2) {
            // Q/K: [b,h,s,d]; lane owns 4 consecutive d -> 8B stores. Q gets QSCALE.
            const float* bp = (mat == 0) ? bq : bk;
            unsigned short* op = (mat == 0) ? Qo : Ko;
            const float sc = (mat == 0) ? QSCALE : 1.0f;
            const float4 b4 = *(const float4*)(bp + fin);
            const int h = fin >> 6, d = fin & 63;
#pragma unroll
            for (int st = 0; st < 8; ++st) {
                const int sg = blockIdx.x * 256 + wm + st * 16 + l16;
                const int b = sg >> 10, s = sg & 1023;
                ushortx4 o4;
                o4[0] = f2bf((acc[ft][st][0] + b4.x) * sc);
                o4[1] = f2bf((acc[ft][st][1] + b4.y) * sc);
                o4[2] = f2bf((acc[ft][st][2] + b4.z) * sc);
                o4[3] = f2bf((acc[ft][st][3] + b4.w) * sc);
                *(ushortx4*)(op + (((size_t)(b * 16 + h) * 1024 + s) * 64 + d)) = o4;
            }
        } else {
            // V: [b,h,d,s'] with per-64-window PV-fragment permutation:
            // s = 64a + nt*16 + q*4 + j -> s' = 64a + ((st>>1)&1)*32 + q*8 + (st&1)*4 + j
            const float4 b4 = *(const float4*)(bv + fin);
#pragma unroll
            for (int r = 0; r < 4; ++r) {
                const int fr = fin + r;
                const int h = fr >> 6, d = fr & 63;
                const float bias = (r == 0) ? b4.x : (r == 1) ? b4.y : (r == 2) ? b4.z : b4.w;
#pragma unroll
                for (int st = 0; st < 8; ++st) {
                    const int sg = blockIdx.x * 256 + wm + st * 16 + l16;
                    const int b = sg >> 10, s = sg & 1023;
                    const int sp = (s & ~63) + ((st >> 1) & 1) * 32 + (l16 >> 2) * 8 +
                                   (st & 1) * 4 + (l16 & 3);
                    Vo[((size_t)(b * 16 + h) * 64 + d) * 1024 + sp] = f2bf(acc[ft][st][r] + bias);
                }
            }
        }
    }
}

// ---------------- flash attention: 128-row Q tile, direct-global Q fragments ----------
// grid (128, 8): x = head, y = 128-row q-tile. Softmax VALU diet (r6 = r5 bisected):
//  - mask folded into QK^T accumulator init (z = mk; MFMA's C-in does the add)
//  - P row-sum via ones-MFMA (idle matrix pipe) instead of 64 scalar adds + shfl;
//    denominator = sum of bf16(p), consistent with the PV numerator.
//  - P f32->bf16 packing: PROVEN shift-truncate (r5's v_cvt_pk_bf16_f32 inline asm
//    produced NaN on gfx950 — do not hand-write cvt_pk; cf. guide m240).
__global__ __launch_bounds__(256) void attn(
    const unsigned short* __restrict__ Q,   // [b,h,s,d] (scaled by 0.125*log2e)
    const unsigned short* __restrict__ Kg,  // [b,h,s,d]
    const unsigned short* __restrict__ Vt,  // [b,h,d,s'] (permuted)
    const float* __restrict__ mask,         // [B][S]
    unsigned short* __restrict__ ctx)       // [B,S,H] bf16
{
    __shared__ unsigned short Ks[64 * 64];
    __shared__ unsigned short Vs[64 * 64];
    __shared__ float Msall[1024];

    const int t = threadIdx.x;
    const int wave = t >> 6, lane = t & 63, quad = lane >> 4, l16 = lane & 15;
    const int s7 = l16 & 7;
    const int head = blockIdx.x;
    const int b = head >> 4, h = head & 15;
    const int q0 = blockIdx.y * 128;
    const unsigned short* Qh = Q + (size_t)head * 65536;
    const unsigned short* Kh = Kg + (size_t)head * 65536;
    const unsigned short* Vh = Vt + (size_t)head * 65536;

    const int srow = t >> 3;
    const int scol = ((t & 7) ^ (srow & 7)) * 8;

    {   // mask row -> LDS, pre-scaled by log2e
        float4 m4 = *(const float4*)(mask + b * 1024 + t * 4);
        m4.x *= LOG2E; m4.y *= LOG2E; m4.z *= LOG2E; m4.w *= LOG2E;
        *(float4*)(Msall + t * 4) = m4;
    }

    // Q fragments direct from global: qf[qg][s][j] = Q[q0+wave*32+qg*16+l16][s*32+quad*8+j]
    bf16x8 qf[2][2];
#pragma unroll
    for (int qg = 0; qg < 2; qg++) {
        const unsigned short* qp = Qh + (size_t)(q0 + wave * 32 + qg * 16 + l16) * 64 + quad * 8;
        qf[qg][0] = *(const bf16x8*)(qp);
        qf[qg][1] = *(const bf16x8*)(qp + 32);
    }

    const short4v ones = {(short)0x3F80, (short)0x3F80, (short)0x3F80, (short)0x3F80};
    floatx4 sum_acc[2] = {};    // all rows identical = full P row-sum per q-col l16
    floatx4 o_acc[2][4] = {};   // [qg][dt]: O^T rows d = dt*16+quad*4+r, col q = l16

    for (int k0 = 0; k0 < 1024; k0 += 64) {
        __syncthreads();
#pragma unroll
        for (int i = 0; i < 2; i++) {
            ASYNC16(Kh + (size_t)(k0 + i * 32 + srow) * 64 + scol, Ks + i * 2048 + t * 8);
            ASYNC16(Vh + (size_t)(i * 32 + srow) * 1024 + k0 + scol, Vs + i * 2048 + t * 8);
        }
        __syncthreads();

        short4v pf0[4], pf1[4];
#pragma unroll
        for (int nt = 0; nt < 4; nt++) {
            int krow = nt * 16 + l16;
            bf16x8 kf0 = *(const bf16x8*)(Ks + krow * 64 + ((quad ^ s7) * 8));
            bf16x8 kf1 = *(const bf16x8*)(Ks + krow * 64 + (((4 + quad) ^ s7) * 8));
            floatx4 mk = *(const floatx4*)(Msall + k0 + nt * 16 + quad * 4);
            floatx4 z0 = mk;   // mask folded into accumulator init
            z0 = mfma32(kf0, qf[0][0], z0);
            z0 = mfma32(kf1, qf[0][1], z0);
            floatx4 z1 = mk;
            z1 = mfma32(kf0, qf[1][0], z1);
            z1 = mfma32(kf1, qf[1][1], z1);
#pragma unroll
            for (int r = 0; r < 4; r++) {
                pf0[nt][r] = (short)(__float_as_uint(exp2f(z0[r])) >> 16);
                pf1[nt][r] = (short)(__float_as_uint(exp2f(z1[r])) >> 16);
            }
            sum_acc[0] = mfma16(ones, pf0[nt], sum_acc[0]);
            sum_acc[1] = mfma16(ones, pf1[nt], sum_acc[1]);
        }

        // O^T += V^T P^T; Vs permuted so (nt,nt+1) fragments are one b128 read.
#pragma unroll
        for (int dt = 0; dt < 4; dt++) {
            int vrow = dt * 16 + l16;
            ushortx8 v01 = *(const ushortx8*)(Vs + vrow * 64 + ((quad ^ s7) * 8));
            ushortx8 v23 = *(const ushortx8*)(Vs + vrow * 64 + (((4 + quad) ^ s7) * 8));
            short4v vf0 = {(short)v01[0], (short)v01[1], (short)v01[2], (short)v01[3]};
            short4v vf1 = {(short)v01[4], (short)v01[5], (short)v01[6], (short)v01[7]};
            short4v vf2 = {(short)v23[0], (short)v23[1], (short)v23[2], (short)v23[3]};
            short4v vf3 = {(short)v23[4], (short)v23[5], (short)v23[6], (short)v23[7]};
            o_acc[0][dt] = mfma16(vf0, pf0[0], o_acc[0][dt]);
            o_acc[0][dt] = mfma16(vf1, pf0[1], o_acc[0][dt]);
            o_acc[0][dt] = mfma16(vf2, pf0[2], o_acc[0][dt]);
            o_acc[0][dt] = mfma16(vf3, pf0[3], o_acc[0][dt]);
            o_acc[1][dt] = mfma16(vf0, pf1[0], o_acc[1][dt]);
            o_acc[1][dt] = mfma16(vf1, pf1[1], o_acc[1][dt]);
            o_acc[1][dt] = mfma16(vf2, pf1[2], o_acc[1][dt]);
            o_acc[1][dt] = mfma16(vf3, pf1[3], o_acc[1][dt]);
        }
    }

#pragma unroll
    for (int qg = 0; qg < 2; qg++) {
        float inv_l = 1.0f / sum_acc[qg][0];
        int qrow = q0 + wave * 32 + qg * 16 + l16;
#pragma unroll
        for (int dt = 0; dt < 4; dt++) {
            ushortx4 o4;
#pragma unroll
            for (int r = 0; r < 4; r++) o4[r] = f2bf(o_acc[qg][dt][r] * inv_l);
            *(ushortx4*)(ctx + ((size_t)(b * 1024 + qrow)) * 1024 + h * 64 + dt * 16 + quad * 4) = o4;
        }
    }
}

// ---------------- out-proj GEMM + bias + bf16 residual -> x (bf16) ----------------
__global__ __launch_bounds__(256) void gemm_proj(
    const unsigned short* __restrict__ A,   // ctx bf16 [8192][1024]
    const unsigned short* __restrict__ W,   // Wo bf16 [1024][1024]
    const float* __restrict__ bo,
    const unsigned short* __restrict__ resid,  // hid_bf [8192][1024]
    unsigned short* __restrict__ X)         // bf16 [8192][1024]
{
    __shared__ unsigned short As[128 * 64];
    __shared__ unsigned short Bs[128 * 64];
    const int t = threadIdx.x;
    const int wave = t >> 6, lane = t & 63;
    const int quad = lane >> 4, l16 = lane & 15;
    const int wm = (wave >> 1) * 64, wn = (wave & 1) * 64;
    const int srow = t >> 3;
    const int scol = ((t & 7) ^ (srow & 7)) * 8;

    const unsigned short* Ag = A + ((size_t)blockIdx.x * 128 + srow) * 1024 + scol;
    const unsigned short* Wg = W + ((size_t)blockIdx.y * 128 + srow) * 1024 + scol;

    floatx4 acc[4][4] = {};
    kloop_bk64<false>(Ag, Wg, As, Bs, wm, wn, l16, quad, t, acc);

#pragma unroll
    for (int nt = 0; nt < 4; nt++) {
        int gn = blockIdx.y * 128 + wn + nt * 16 + l16;
        float bias = bo[gn];
#pragma unroll
        for (int mt = 0; mt < 4; mt++) {
#pragma unroll
            for (int r = 0; r < 4; r++) {
                int gm = blockIdx.x * 128 + wm + mt * 16 + quad * 4 + r;
                size_t off = (size_t)gm * 1024 + gn;
                X[off] = f2bf(acc[mt][nt][r] + bias + bf2f(resid[off]));
            }
        }
    }
}

// ---------------- LayerNorm: one block per token row (bf16 in, fp32 out) ------------
__global__ __launch_bounds__(256) void ln_k(const unsigned short* __restrict__ X,
                                            const float* __restrict__ g,
                                            const float* __restrict__ be,
                                            float* __restrict__ out)
{
    int row = blockIdx.x;
    int t = threadIdx.x;
    const unsigned short* xr = X + (size_t)row * 1024;
    ushortx4 xb = *(const ushortx4*)(xr + t * 4);
    float4 v;
    v.x = bf2f(xb[0]);
    v.y = bf2f(xb[1]);
    v.z = bf2f(xb[2]);
    v.w = bf2f(xb[3]);
    float s = v.x + v.y + v.z + v.w;
    float ss = v.x * v.x + v.y * v.y + v.z * v.z + v.w * v.w;
    for (int off = 1; off < 64; off <<= 1) {
        s += __shfl_xor(s, off);
        ss += __shfl_xor(ss, off);
    }
    __shared__ float red[8];
    int wave = t >> 6, lane = t & 63;
    if (lane == 0) { red[wave] = s; red[4 + wave] = ss; }
    __syncthreads();
    s = red[0] + red[1] + red[2] + red[3];
    ss = red[4] + red[5] + red[6] + red[7];
    float mu = s * (1.f / 1024.f);
    float var = ss * (1.f / 1024.f) - mu * mu;
    float inv = rsqrtf(var + 1e-12f);
    float4 gv = *(const float4*)(g + t * 4);
    float4 bv = *(const float4*)(be + t * 4);
    float4 o;
    o.x = (v.x - mu) * inv * gv.x + bv.x;
    o.y = (v.y - mu) * inv * gv.y + bv.y;
    o.z = (v.z - mu) * inv * gv.z + bv.z;
    o.w = (v.w - mu) * inv * gv.w + bv.w;
    *(float4*)(out + (size_t)row * 1024 + t * 4) = o;
}

extern "C" void kernel_launch(void* const* d_in, const int* in_sizes, int n_in,
                              void* d_out, int out_size, void* d_ws, size_t ws_size,
                              hipStream_t stream)
{
    const float* hidden = (const float*)d_in[0];
    const float* mask   = (const float*)d_in[1];
    const float* Wq = (const float*)d_in[2];
    const float* bq = (const float*)d_in[3];
    const float* Wk = (const float*)d_in[4];
    const float* bk = (const float*)d_in[5];
    const float* Wv = (const float*)d_in[6];
    const float* bv = (const float*)d_in[7];
    const float* Wo = (const float*)d_in[8];
    const float* bo = (const float*)d_in[9];
    const float* gamma = (const float*)d_in[10];
    const float* beta  = (const float*)d_in[11];
    float* out = (float*)d_out;

    char* ws = (char*)d_ws;
    // layout (bytes): hid_bf 16M | wqkv_bf 6M | wo_bf 2M | vt_bf 16M | ctx_bf 16M | q_bf 16M | k_bf 16M
    // x (bf16, 16M) aliases q_bf (dead after attn). total 88M.
    unsigned short* hid_bf  = (unsigned short*)(ws + 0);
    unsigned short* wqkv_bf = (unsigned short*)(ws + 16777216);
    unsigned short* wo_bf   = (unsigned short*)(ws + 23068672);
    unsigned short* vt_bf   = (unsigned short*)(ws + 25165824);
    unsigned short* ctx_bf  = (unsigned short*)(ws + 41943040);
    unsigned short* q_bf    = (unsigned short*)(ws + 58720256);
    unsigned short* k_bf    = (unsigned short*)(ws + 75497472);
    unsigned short* x_bf    = (unsigned short*)(ws + 58720256);

    cvt_all<<<6144, 256, 0, stream>>>(hidden, Wq, Wk, Wv, Wo, hid_bf, wqkv_bf, wo_bf);

    gemm_qkv<<<dim3(32, 16), 512, 0, stream>>>(hid_bf, wqkv_bf, bq, bk, bv, q_bf, k_bf, vt_bf);
    attn<<<dim3(128, 8), 256, 0, stream>>>(q_bf, k_bf, vt_bf, mask, ctx_bf);
    gemm_proj<<<dim3(64, 8), 256, 0, stream>>>(ctx_bf, wo_bf, bo, hid_bf, x_bf);
    ln_k<<<8192, 256, 0, stream>>>(x_bf, gamma, beta, out);
}